// Round 1
// baseline (2665.022 us; speedup 1.0000x reference)
//
#include <hip/hip_runtime.h>
#include <cmath>

typedef __bf16 bf16;
typedef float f32x4 __attribute__((ext_vector_type(4)));
typedef __bf16 bf16x4 __attribute__((ext_vector_type(4)));
typedef __bf16 bf16x8 __attribute__((ext_vector_type(8)));

#define DEVI __device__ __forceinline__

// ---- problem dims ----
constexpr int Bn = 4, Tn = 2048, Cn = 1024, Hn = 16, HSn = 64;
constexpr int C3n = 3 * Cn;      // 3072
constexpr int BTn = Bn * Tn;     // 8192

// ---- workspace layout (bytes) ----
constexpr size_t OFF_WT_QKV = 0;           // 3072x1024 bf16 = 6291456
constexpr size_t OFF_WT_O   = 6291456;     // 1024x1024 bf16 = 2097152
constexpr size_t OFF_WT_FC  = 8388608;     // 4096x1024 bf16 = 8388608
constexpr size_t OFF_WT_PR  = 16777216;    // 1024x4096 bf16 = 8388608
constexpr size_t OFF_H      = 25165824;    // 8192x1024 bf16 = 16777216 (h / h2)
constexpr size_t OFF_Y      = 41943040;    // 8192x1024 bf16 = 16777216 (attn out)
constexpr size_t OFF_X1     = 58720256;    // 8192x1024 f32  = 33554432 (resid1)
constexpr size_t OFF_AMAX   = 92274688;    // 2 x u32
constexpr size_t OFF_QKV    = 92274944;    // 8192x3072 bf16 = 50331648
constexpr size_t OFF_G      = OFF_QKV;     // 8192x4096 bf16 = 67108864 (aliases qkv, dead by then)
// total needed = 159,383,808 bytes

// ---- d_out layout (float elements) ----
constexpr size_t OUT_X  = 0;          // (B,T,C)     8388608
constexpr size_t OUT_KQ = 8388608;    // (B,H,T,HS)  8388608
constexpr size_t OUT_KS = 16777216;   // scalar
constexpr size_t OUT_VQ = 16777217;   // (B,H,T,HS)  8388608
constexpr size_t OUT_VS = 25165825;   // scalar

// ============================================================
// async global->LDS, 16B per lane. LDS dst must be wave-uniform base;
// HW places lane i at base + i*16.
DEVI void g2l16(const void* g, void* l) {
  __builtin_amdgcn_global_load_lds(
      (__attribute__((address_space(1))) void*)g,
      (__attribute__((address_space(3))) void*)l, 16, 0, 0);
}

// ============================================================
// transpose + cast: W (K x N) f32 -> Wt (N x K) bf16
__global__ __launch_bounds__(256) void k_transpose(const float* __restrict__ W,
                                                   bf16* __restrict__ Wt,
                                                   int K, int N) {
  __shared__ float tile[32][33];
  const int n0 = blockIdx.x * 32, k0 = blockIdx.y * 32;
  const int tx = threadIdx.x, ty = threadIdx.y;   // block (32,8)
#pragma unroll
  for (int i = 0; i < 4; ++i) {
    int k = k0 + ty + i * 8;
    tile[ty + i * 8][tx] = W[(size_t)k * N + (n0 + tx)];
  }
  __syncthreads();
#pragma unroll
  for (int i = 0; i < 4; ++i) {
    int n = n0 + ty + i * 8;
    Wt[(size_t)n * K + (k0 + tx)] = (bf16)tile[tx][ty + i * 8];
  }
}

// ============================================================
// LayerNorm row of 1024, f32 in -> bf16 out. 256 threads/row, 4 elems/thread.
__global__ __launch_bounds__(256) void k_ln(const float* __restrict__ x,
                                            const float* __restrict__ g,
                                            const float* __restrict__ b,
                                            bf16* __restrict__ out) {
  __shared__ float red[8];
  const int row = blockIdx.x, tid = threadIdx.x;
  const int lane = tid & 63, wv = tid >> 6;
  f32x4 v = ((const f32x4*)(x + (size_t)row * Cn))[tid];

  float s = v[0] + v[1] + v[2] + v[3];
  s += __shfl_down(s, 32); s += __shfl_down(s, 16); s += __shfl_down(s, 8);
  s += __shfl_down(s, 4);  s += __shfl_down(s, 2);  s += __shfl_down(s, 1);
  if (!lane) red[wv] = s;
  __syncthreads();
  const float mean = (red[0] + red[1] + red[2] + red[3]) * (1.0f / 1024.0f);
  __syncthreads();

  f32x4 d = v - mean;
  float s2 = d[0]*d[0] + d[1]*d[1] + d[2]*d[2] + d[3]*d[3];
  s2 += __shfl_down(s2, 32); s2 += __shfl_down(s2, 16); s2 += __shfl_down(s2, 8);
  s2 += __shfl_down(s2, 4);  s2 += __shfl_down(s2, 2);  s2 += __shfl_down(s2, 1);
  if (!lane) red[wv] = s2;
  __syncthreads();
  const float var = (red[0] + red[1] + red[2] + red[3]) * (1.0f / 1024.0f);
  const float inv = rsqrtf(var + 1e-5f);

  f32x4 gw = ((const f32x4*)g)[tid];
  f32x4 bb = ((const f32x4*)b)[tid];
  bf16x4 o;
#pragma unroll
  for (int j = 0; j < 4; ++j) o[j] = (bf16)(d[j] * inv * gw[j] + bb[j]);
  *(bf16x4*)(out + (size_t)row * Cn + tid * 4) = o;
}

// ============================================================
// MFMA GEMM: C(MxN) = A(MxK,bf16) * Bt(NxK,bf16)^T + bias [+GELU] [+res]
// 128x128 block tile, 4 waves (2x2), each wave 4x4 of 16x16x32 mfma, BK=32.
template <bool BF16OUT, bool RES, bool GELU>
__global__ __launch_bounds__(256) void k_gemm(const bf16* __restrict__ A,
                                              const bf16* __restrict__ Bt,
                                              const float* __restrict__ bias,
                                              const float* __restrict__ res,
                                              void* __restrict__ Cout,
                                              int M, int N, int K) {
  __shared__ bf16 As[128 * 32];
  __shared__ bf16 Bs[128 * 32];
  const int tid = threadIdx.x;
  const int lane = tid & 63;
  const int w = tid >> 6;
  const int wm = w & 1, wn = w >> 1;
  const int m0 = blockIdx.x * 128, n0 = blockIdx.y * 128;

  // staging: lane l of wave w loads row 16w + (l>>2) (+64 for 2nd issue),
  // k-chunk (l&3)*8; HW writes LDS at (wave base) + l*16B -> row-major [128][32].
  const bf16* aSrc = A  + (size_t)(m0 + (tid >> 2)) * K + (tid & 3) * 8;
  const bf16* bSrc = Bt + (size_t)(n0 + (tid >> 2)) * K + (tid & 3) * 8;
  bf16* aDst = As + 512 * w;
  bf16* bDst = Bs + 512 * w;

  // fragment bases: A[m=lane&15][k=quad*8+j], B from Bt rows (n=lane&15)
  const bf16* aFrag = As + (wm * 64 + (lane & 15)) * 32 + (lane >> 4) * 8;
  const bf16* bFrag = Bs + (wn * 64 + (lane & 15)) * 32 + (lane >> 4) * 8;

  f32x4 acc[4][4] = {};
  const int kIters = K >> 5;
  for (int kt = 0; kt < kIters; ++kt) {
    g2l16(aSrc, aDst);
    g2l16(aSrc + (size_t)64 * K, aDst + 2048);
    g2l16(bSrc, bDst);
    g2l16(bSrc + (size_t)64 * K, bDst + 2048);
    aSrc += 32; bSrc += 32;
    __builtin_amdgcn_s_waitcnt(0);
    __syncthreads();

    bf16x8 af[4], bv[4];
#pragma unroll
    for (int mt = 0; mt < 4; ++mt) af[mt] = *(const bf16x8*)(aFrag + mt * 512);
#pragma unroll
    for (int nt = 0; nt < 4; ++nt) bv[nt] = *(const bf16x8*)(bFrag + nt * 512);
#pragma unroll
    for (int mt = 0; mt < 4; ++mt)
#pragma unroll
      for (int nt = 0; nt < 4; ++nt)
        acc[mt][nt] = __builtin_amdgcn_mfma_f32_16x16x32_bf16(af[mt], bv[nt], acc[mt][nt], 0, 0, 0);
    __syncthreads();
  }

  // epilogue; C/D layout: col = lane&15, row = quad*4 + r
  const int colB = n0 + wn * 64 + (lane & 15);
  const int rowB = m0 + wm * 64 + ((lane >> 4) << 2);
#pragma unroll
  for (int mt = 0; mt < 4; ++mt) {
#pragma unroll
    for (int nt = 0; nt < 4; ++nt) {
      const int col = colB + nt * 16;
      const float bval = bias[col];
#pragma unroll
      for (int r = 0; r < 4; ++r) {
        const int row = rowB + mt * 16 + r;
        float val = acc[mt][nt][r] + bval;
        if (GELU) val = 0.5f * val * (1.0f + erff(val * 0.7071067811865476f));
        if (RES)  val += res[(size_t)row * N + col];
        if (BF16OUT) ((bf16*)Cout)[(size_t)row * N + col] = (bf16)val;
        else         ((float*)Cout)[(size_t)row * N + col] = val;
      }
    }
  }
}

// ============================================================
// per-tensor absmax over K and V slices of qkv (bf16 (B,T,3C))
__global__ __launch_bounds__(256) void k_init(unsigned int* amax) {
  if (threadIdx.x < 2) amax[threadIdx.x] = 0u;
}

__global__ __launch_bounds__(256) void k_absmax(const bf16* __restrict__ qkv,
                                                unsigned int* __restrict__ amax) {
  __shared__ float redk[4], redv[4];
  float mk = 0.0f, mv = 0.0f;
  const size_t nchunks = (size_t)BTn * 128;   // 8 elems per chunk
  const size_t stride = (size_t)gridDim.x * blockDim.x;
  for (size_t ci = (size_t)blockIdx.x * blockDim.x + threadIdx.x; ci < nchunks; ci += stride) {
    const size_t bt = ci >> 7;
    const int c8 = (int)(ci & 127) * 8;
    const bf16* base = qkv + bt * C3n + c8;
    bf16x8 k8 = *(const bf16x8*)(base + Cn);
    bf16x8 v8 = *(const bf16x8*)(base + 2 * Cn);
#pragma unroll
    for (int j = 0; j < 8; ++j) {
      mk = fmaxf(mk, fabsf((float)k8[j]));
      mv = fmaxf(mv, fabsf((float)v8[j]));
    }
  }
  for (int off = 32; off; off >>= 1) {
    mk = fmaxf(mk, __shfl_down(mk, off));
    mv = fmaxf(mv, __shfl_down(mv, off));
  }
  const int lane = threadIdx.x & 63, wv = threadIdx.x >> 6;
  if (!lane) { redk[wv] = mk; redv[wv] = mv; }
  __syncthreads();
  if (threadIdx.x == 0) {
    mk = fmaxf(fmaxf(redk[0], redk[1]), fmaxf(redk[2], redk[3]));
    mv = fmaxf(fmaxf(redv[0], redv[1]), fmaxf(redv[2], redv[3]));
    atomicMax(amax + 0, __float_as_uint(mk));   // nonneg floats: uint order == float order
    atomicMax(amax + 1, __float_as_uint(mv));
  }
}

// quantize K,V -> d_out (as floats), layout (B,H,T,HS); also write scales
__global__ __launch_bounds__(256) void k_quant(const bf16* __restrict__ qkv,
                                               const unsigned int* __restrict__ amax,
                                               float* __restrict__ out) {
  const float ka = __uint_as_float(amax[0]);
  const float va = __uint_as_float(amax[1]);
  const float ks = ka > 0.0f ? ka / 127.0f : 1.0f;
  const float vs = va > 0.0f ? va / 127.0f : 1.0f;
  if (blockIdx.x == 0 && threadIdx.x == 0) { out[OUT_KS] = ks; out[OUT_VS] = vs; }
  const float kinv = 1.0f / ks, vinv = 1.0f / vs;
  const size_t nchunks = 1048576;  // 8.39M elems / 8
  const size_t stride = (size_t)gridDim.x * blockDim.x;
  for (size_t ci = (size_t)blockIdx.x * blockDim.x + threadIdx.x; ci < nchunks; ci += stride) {
    const int d0 = (int)(ci & 7) * 8;
    const int t  = (int)(ci >> 3) & 2047;
    const int h  = (int)(ci >> 14) & 15;
    const int b  = (int)(ci >> 18);
    const size_t src = ((size_t)(b * Tn + t)) * C3n + h * HSn + d0;
    bf16x8 k8 = *(const bf16x8*)(qkv + src + Cn);
    bf16x8 v8 = *(const bf16x8*)(qkv + src + 2 * Cn);
    float kq[8], vq[8];
#pragma unroll
    for (int j = 0; j < 8; ++j) {
      kq[j] = fminf(fmaxf(rintf((float)k8[j] * kinv), -127.0f), 127.0f);
      vq[j] = fminf(fmaxf(rintf((float)v8[j] * vinv), -127.0f), 127.0f);
    }
    const size_t oi = ci * 8;
    f32x4 a0 = {kq[0], kq[1], kq[2], kq[3]};
    f32x4 a1 = {kq[4], kq[5], kq[6], kq[7]};
    *(f32x4*)(out + OUT_KQ + oi)     = a0;   // OUT_KQ + 8ci is 16B aligned
    *(f32x4*)(out + OUT_KQ + oi + 4) = a1;
    float* vdst = out + OUT_VQ + oi;         // OUT_VQ is odd -> scalar stores
#pragma unroll
    for (int j = 0; j < 8; ++j) vdst[j] = vq[j];
  }
}

// ============================================================
// fp32 vector flash attention, causal. One block per (b,h,qtile of 64).
// S tile 64x64: thread (tq,tk) owns S[4q][4k]; O owned as [4q][4d] (d=tk*4+j).
__global__ __launch_bounds__(256) void k_attn(const bf16* __restrict__ qkv,
                                              bf16* __restrict__ y) {
  __shared__ float Qs[64][68];
  __shared__ float Ks[64][68];
  __shared__ float Vs[64][68];
  float (*Ps)[68] = Ks;   // P overwrites K after S is computed

  const int tid = threadIdx.x;
  const int tq = tid >> 4, tk = tid & 15;
  const int qt = blockIdx.x;
  const int bh = blockIdx.y;
  const int b = bh >> 4, h = bh & 15;
  const int q0 = qt * 64;

  const bf16* qb = qkv + ((size_t)b * Tn + q0) * C3n + h * HSn;
  const bf16* kb = qkv + (size_t)b * Tn * C3n + Cn + h * HSn;
  const bf16* vb = kb + Cn;

  // load Q tile (pre-scaled by 1/sqrt(64))
  for (int c = tid; c < 512; c += 256) {
    const int r = c >> 3, c8 = (c & 7) * 8;
    bf16x8 q8 = *(const bf16x8*)(qb + (size_t)r * C3n + c8);
#pragma unroll
    for (int j = 0; j < 8; ++j) Qs[r][c8 + j] = (float)q8[j] * 0.125f;
  }

  f32x4 O[4] = {};
  float m_i[4] = {-INFINITY, -INFINITY, -INFINITY, -INFINITY};
  float l_i[4] = {};

  for (int kt = 0; kt <= qt; ++kt) {
    const int kv0 = kt * 64;
    __syncthreads();   // prev PV done (and Q visible on first iter)
    for (int c = tid; c < 512; c += 256) {
      const int r = c >> 3, c8 = (c & 7) * 8;
      const size_t off = (size_t)(kv0 + r) * C3n + c8;
      bf16x8 k8 = *(const bf16x8*)(kb + off);
      bf16x8 v8 = *(const bf16x8*)(vb + off);
#pragma unroll
      for (int j = 0; j < 8; ++j) { Ks[r][c8 + j] = (float)k8[j]; Vs[r][c8 + j] = (float)v8[j]; }
    }
    __syncthreads();

    // S = Q K^T (Q pre-scaled)
    f32x4 S[4] = {};
    for (int dd = 0; dd < 64; dd += 4) {
      f32x4 qv[4], kv[4];
#pragma unroll
      for (int i = 0; i < 4; ++i) qv[i] = *(const f32x4*)&Qs[tq * 4 + i][dd];
#pragma unroll
      for (int j = 0; j < 4; ++j) kv[j] = *(const f32x4*)&Ks[tk * 4 + j][dd];
#pragma unroll
      for (int i = 0; i < 4; ++i)
#pragma unroll
        for (int j = 0; j < 4; ++j)
          S[i][j] += qv[i][0]*kv[j][0] + qv[i][1]*kv[j][1] + qv[i][2]*kv[j][2] + qv[i][3]*kv[j][3];
    }
    if (kt == qt) {   // diagonal tile: causal mask (same tile base)
#pragma unroll
      for (int i = 0; i < 4; ++i)
#pragma unroll
        for (int j = 0; j < 4; ++j)
          if (tk * 4 + j > tq * 4 + i) S[i][j] = -INFINITY;
    }
    __syncthreads();   // everyone done reading Ks before P overwrites it

    // online softmax update + P write
#pragma unroll
    for (int i = 0; i < 4; ++i) {
      float mx = fmaxf(fmaxf(S[i][0], S[i][1]), fmaxf(S[i][2], S[i][3]));
      for (int off = 1; off < 16; off <<= 1) mx = fmaxf(mx, __shfl_xor(mx, off));
      const float mn = fmaxf(m_i[i], mx);
      const float al = __expf(m_i[i] - mn);   // first iter: exp(-inf)=0
      m_i[i] = mn;
      f32x4 p;
#pragma unroll
      for (int j = 0; j < 4; ++j) p[j] = __expf(S[i][j] - mn);
      float rsum = p[0] + p[1] + p[2] + p[3];
      for (int off = 1; off < 16; off <<= 1) rsum += __shfl_xor(rsum, off);
      l_i[i] = l_i[i] * al + rsum;
      O[i] *= al;
      *(f32x4*)&Ps[tq * 4 + i][tk * 4] = p;
    }
    __syncthreads();   // P visible

    // O += P V
    for (int kk = 0; kk < 64; kk += 4) {
      f32x4 pv4[4], vv[4];
#pragma unroll
      for (int i = 0; i < 4; ++i) pv4[i] = *(const f32x4*)&Ps[tq * 4 + i][kk];
#pragma unroll
      for (int t4 = 0; t4 < 4; ++t4) vv[t4] = *(const f32x4*)&Vs[kk + t4][tk * 4];
#pragma unroll
      for (int i = 0; i < 4; ++i)
        O[i] += pv4[i][0]*vv[0] + pv4[i][1]*vv[1] + pv4[i][2]*vv[2] + pv4[i][3]*vv[3];
    }
  }

  // write y (B,T,C) bf16
  const size_t yb = ((size_t)b * Tn + q0) * Cn + h * HSn;
#pragma unroll
  for (int i = 0; i < 4; ++i) {
    const float inv = 1.0f / l_i[i];
    bf16x4 o;
#pragma unroll
    for (int j = 0; j < 4; ++j) o[j] = (bf16)(O[i][j] * inv);
    *(bf16x4*)(y + yb + (size_t)(tq * 4 + i) * Cn + tk * 4) = o;
  }
}

// ============================================================
extern "C" void kernel_launch(void* const* d_in, const int* in_sizes, int n_in,
                              void* d_out, int out_size, void* d_ws, size_t ws_size,
                              hipStream_t stream) {
  const float* x     = (const float*)d_in[0];
  const float* ln1w  = (const float*)d_in[1];
  const float* ln1b  = (const float*)d_in[2];
  const float* Wqkv  = (const float*)d_in[3];
  const float* bqkv  = (const float*)d_in[4];
  const float* Wo    = (const float*)d_in[5];
  const float* bo    = (const float*)d_in[6];
  const float* ln2w  = (const float*)d_in[7];
  const float* ln2b  = (const float*)d_in[8];
  const float* Wfc   = (const float*)d_in[9];
  const float* bfc   = (const float*)d_in[10];
  const float* Wpr   = (const float*)d_in[11];
  const float* bpr   = (const float*)d_in[12];

  char* ws = (char*)d_ws;
  bf16*  Wt_qkv = (bf16*)(ws + OFF_WT_QKV);
  bf16*  Wt_o   = (bf16*)(ws + OFF_WT_O);
  bf16*  Wt_fc  = (bf16*)(ws + OFF_WT_FC);
  bf16*  Wt_pr  = (bf16*)(ws + OFF_WT_PR);
  bf16*  h      = (bf16*)(ws + OFF_H);
  bf16*  ybf    = (bf16*)(ws + OFF_Y);
  float* x1     = (float*)(ws + OFF_X1);
  unsigned int* amax = (unsigned int*)(ws + OFF_AMAX);
  bf16*  qkvbf  = (bf16*)(ws + OFF_QKV);
  bf16*  g      = (bf16*)(ws + OFF_G);
  float* out    = (float*)d_out;

  const dim3 tb(32, 8);
  k_transpose<<<dim3(96, 32),  tb, 0, stream>>>(Wqkv, Wt_qkv, 1024, 3072);
  k_transpose<<<dim3(32, 32),  tb, 0, stream>>>(Wo,   Wt_o,   1024, 1024);
  k_transpose<<<dim3(128, 32), tb, 0, stream>>>(Wfc,  Wt_fc,  1024, 4096);
  k_transpose<<<dim3(32, 128), tb, 0, stream>>>(Wpr,  Wt_pr,  4096, 1024);
  k_init<<<1, 64, 0, stream>>>(amax);

  // h = LN1(x)
  k_ln<<<BTn, 256, 0, stream>>>(x, ln1w, ln1b, h);
  // qkv = h @ Wqkv + bqkv   (bf16 out)
  k_gemm<true, false, false><<<dim3(64, 24), 256, 0, stream>>>(h, Wt_qkv, bqkv, nullptr, qkvbf, 8192, 3072, 1024);
  // int8 KV-cache emit
  k_absmax<<<1024, 256, 0, stream>>>(qkvbf, amax);
  k_quant<<<2048, 256, 0, stream>>>(qkvbf, amax, out);
  // causal SDPA
  k_attn<<<dim3(32, 64), 256, 0, stream>>>(qkvbf, ybf);
  // x1 = x + y @ Wo + bo    (f32 out)
  k_gemm<false, true, false><<<dim3(64, 8), 256, 0, stream>>>(ybf, Wt_o, bo, x, x1, 8192, 1024, 1024);
  // h2 = LN2(x1)
  k_ln<<<BTn, 256, 0, stream>>>(x1, ln2w, ln2b, h);
  // g = gelu(h2 @ Wfc + bfc)  (bf16 out)
  k_gemm<true, false, true><<<dim3(64, 32), 256, 0, stream>>>(h, Wt_fc, bfc, nullptr, g, 8192, 4096, 1024);
  // out = x1 + g @ Wpr + bpr  (f32 out -> d_out)
  k_gemm<false, true, false><<<dim3(64, 8), 256, 0, stream>>>(g, Wt_pr, bpr, x1, out, 8192, 1024, 4096);
}

// Round 2
// 798.886 us; speedup vs baseline: 3.3359x; 3.3359x over previous
//
#include <hip/hip_runtime.h>
#include <cmath>

typedef __bf16 bf16;
typedef float f32x4 __attribute__((ext_vector_type(4)));
typedef __bf16 bf16x4 __attribute__((ext_vector_type(4)));
typedef __bf16 bf16x8 __attribute__((ext_vector_type(8)));

#define DEVI __device__ __forceinline__

// ---- problem dims ----
constexpr int Bn = 4, Tn = 2048, Cn = 1024, Hn = 16, HSn = 64;
constexpr int C3n = 3 * Cn;      // 3072
constexpr int BTn = Bn * Tn;     // 8192

// ---- workspace layout (bytes) ----
constexpr size_t OFF_WT_QKV = 0;           // 3072x1024 bf16
constexpr size_t OFF_WT_O   = 6291456;     // 1024x1024 bf16
constexpr size_t OFF_WT_FC  = 8388608;     // 4096x1024 bf16
constexpr size_t OFF_WT_PR  = 16777216;    // 1024x4096 bf16
constexpr size_t OFF_H      = 25165824;    // 8192x1024 bf16 (h / h2)
constexpr size_t OFF_Y      = 41943040;    // 8192x1024 bf16 (attn out)
constexpr size_t OFF_X1     = 58720256;    // 8192x1024 f32  (resid1)
constexpr size_t OFF_AMAX   = 92274688;    // 2 x u32
constexpr size_t OFF_QKV    = 92274944;    // 8192x3072 bf16
constexpr size_t OFF_G      = OFF_QKV;     // 8192x4096 bf16 (aliases qkv, dead by then)

// ---- d_out layout (float elements) ----
constexpr size_t OUT_X  = 0;          // (B,T,C)
constexpr size_t OUT_KQ = 8388608;    // (B,H,T,HS)
constexpr size_t OUT_KS = 16777216;   // scalar
constexpr size_t OUT_VQ = 16777217;   // (B,H,T,HS)
constexpr size_t OUT_VS = 25165825;   // scalar

// ============================================================
DEVI void g2l16(const void* g, void* l) {
  __builtin_amdgcn_global_load_lds(
      (__attribute__((address_space(1))) void*)g,
      (__attribute__((address_space(3))) void*)l, 16, 0, 0);
}

// ============================================================
// transpose + cast: W (K x N) f32 -> Wt (N x K) bf16
__global__ __launch_bounds__(256) void k_transpose(const float* __restrict__ W,
                                                   bf16* __restrict__ Wt,
                                                   int K, int N) {
  __shared__ float tile[32][33];
  const int n0 = blockIdx.x * 32, k0 = blockIdx.y * 32;
  const int tx = threadIdx.x, ty = threadIdx.y;   // block (32,8)
#pragma unroll
  for (int i = 0; i < 4; ++i) {
    int k = k0 + ty + i * 8;
    tile[ty + i * 8][tx] = W[(size_t)k * N + (n0 + tx)];
  }
  __syncthreads();
#pragma unroll
  for (int i = 0; i < 4; ++i) {
    int n = n0 + ty + i * 8;
    Wt[(size_t)n * K + (k0 + tx)] = (bf16)tile[tx][ty + i * 8];
  }
}

// ============================================================
// LayerNorm row of 1024, f32 in -> bf16 out.
__global__ __launch_bounds__(256) void k_ln(const float* __restrict__ x,
                                            const float* __restrict__ g,
                                            const float* __restrict__ b,
                                            bf16* __restrict__ out) {
  __shared__ float red[8];
  const int row = blockIdx.x, tid = threadIdx.x;
  const int lane = tid & 63, wv = tid >> 6;
  f32x4 v = ((const f32x4*)(x + (size_t)row * Cn))[tid];

  float s = v[0] + v[1] + v[2] + v[3];
  s += __shfl_down(s, 32); s += __shfl_down(s, 16); s += __shfl_down(s, 8);
  s += __shfl_down(s, 4);  s += __shfl_down(s, 2);  s += __shfl_down(s, 1);
  if (!lane) red[wv] = s;
  __syncthreads();
  const float mean = (red[0] + red[1] + red[2] + red[3]) * (1.0f / 1024.0f);
  __syncthreads();

  f32x4 d = v - mean;
  float s2 = d[0]*d[0] + d[1]*d[1] + d[2]*d[2] + d[3]*d[3];
  s2 += __shfl_down(s2, 32); s2 += __shfl_down(s2, 16); s2 += __shfl_down(s2, 8);
  s2 += __shfl_down(s2, 4);  s2 += __shfl_down(s2, 2);  s2 += __shfl_down(s2, 1);
  if (!lane) red[wv] = s2;
  __syncthreads();
  const float var = (red[0] + red[1] + red[2] + red[3]) * (1.0f / 1024.0f);
  const float inv = rsqrtf(var + 1e-5f);

  f32x4 gw = ((const f32x4*)g)[tid];
  f32x4 bb = ((const f32x4*)b)[tid];
  bf16x4 o;
#pragma unroll
  for (int j = 0; j < 4; ++j) o[j] = (bf16)(d[j] * inv * gw[j] + bb[j]);
  *(bf16x4*)(out + (size_t)row * Cn + tid * 4) = o;
}

// ============================================================
// MFMA GEMM: C(MxN) = A(MxK,bf16) * Bt(NxK,bf16)^T + bias [+GELU] [+res]
template <bool BF16OUT, bool RES, bool GELU>
__global__ __launch_bounds__(256) void k_gemm(const bf16* __restrict__ A,
                                              const bf16* __restrict__ Bt,
                                              const float* __restrict__ bias,
                                              const float* __restrict__ res,
                                              void* __restrict__ Cout,
                                              int M, int N, int K) {
  __shared__ bf16 As[128 * 32];
  __shared__ bf16 Bs[128 * 32];
  const int tid = threadIdx.x;
  const int lane = tid & 63;
  const int w = tid >> 6;
  const int wm = w & 1, wn = w >> 1;
  const int m0 = blockIdx.x * 128, n0 = blockIdx.y * 128;

  const bf16* aSrc = A  + (size_t)(m0 + (tid >> 2)) * K + (tid & 3) * 8;
  const bf16* bSrc = Bt + (size_t)(n0 + (tid >> 2)) * K + (tid & 3) * 8;
  bf16* aDst = As + 512 * w;
  bf16* bDst = Bs + 512 * w;

  const bf16* aFrag = As + (wm * 64 + (lane & 15)) * 32 + (lane >> 4) * 8;
  const bf16* bFrag = Bs + (wn * 64 + (lane & 15)) * 32 + (lane >> 4) * 8;

  f32x4 acc[4][4] = {};
  const int kIters = K >> 5;
  for (int kt = 0; kt < kIters; ++kt) {
    g2l16(aSrc, aDst);
    g2l16(aSrc + (size_t)64 * K, aDst + 2048);
    g2l16(bSrc, bDst);
    g2l16(bSrc + (size_t)64 * K, bDst + 2048);
    aSrc += 32; bSrc += 32;
    __builtin_amdgcn_s_waitcnt(0);
    __syncthreads();

    bf16x8 af[4], bv[4];
#pragma unroll
    for (int mt = 0; mt < 4; ++mt) af[mt] = *(const bf16x8*)(aFrag + mt * 512);
#pragma unroll
    for (int nt = 0; nt < 4; ++nt) bv[nt] = *(const bf16x8*)(bFrag + nt * 512);
#pragma unroll
    for (int mt = 0; mt < 4; ++mt)
#pragma unroll
      for (int nt = 0; nt < 4; ++nt)
        acc[mt][nt] = __builtin_amdgcn_mfma_f32_16x16x32_bf16(af[mt], bv[nt], acc[mt][nt], 0, 0, 0);
    __syncthreads();
  }

  const int colB = n0 + wn * 64 + (lane & 15);
  const int rowB = m0 + wm * 64 + ((lane >> 4) << 2);
#pragma unroll
  for (int mt = 0; mt < 4; ++mt) {
#pragma unroll
    for (int nt = 0; nt < 4; ++nt) {
      const int col = colB + nt * 16;
      const float bval = bias[col];
#pragma unroll
      for (int r = 0; r < 4; ++r) {
        const int row = rowB + mt * 16 + r;
        float val = acc[mt][nt][r] + bval;
        if (GELU) val = 0.5f * val * (1.0f + erff(val * 0.7071067811865476f));
        if (RES)  val += res[(size_t)row * N + col];
        if (BF16OUT) ((bf16*)Cout)[(size_t)row * N + col] = (bf16)val;
        else         ((float*)Cout)[(size_t)row * N + col] = val;
      }
    }
  }
}

// ============================================================
__global__ __launch_bounds__(256) void k_init(unsigned int* amax) {
  if (threadIdx.x < 2) amax[threadIdx.x] = 0u;
}

__global__ __launch_bounds__(256) void k_absmax(const bf16* __restrict__ qkv,
                                                unsigned int* __restrict__ amax) {
  __shared__ float redk[4], redv[4];
  float mk = 0.0f, mv = 0.0f;
  const size_t nchunks = (size_t)BTn * 128;
  const size_t stride = (size_t)gridDim.x * blockDim.x;
  for (size_t ci = (size_t)blockIdx.x * blockDim.x + threadIdx.x; ci < nchunks; ci += stride) {
    const size_t bt = ci >> 7;
    const int c8 = (int)(ci & 127) * 8;
    const bf16* base = qkv + bt * C3n + c8;
    bf16x8 k8 = *(const bf16x8*)(base + Cn);
    bf16x8 v8 = *(const bf16x8*)(base + 2 * Cn);
#pragma unroll
    for (int j = 0; j < 8; ++j) {
      mk = fmaxf(mk, fabsf((float)k8[j]));
      mv = fmaxf(mv, fabsf((float)v8[j]));
    }
  }
  for (int off = 32; off; off >>= 1) {
    mk = fmaxf(mk, __shfl_down(mk, off));
    mv = fmaxf(mv, __shfl_down(mv, off));
  }
  const int lane = threadIdx.x & 63, wv = threadIdx.x >> 6;
  if (!lane) { redk[wv] = mk; redv[wv] = mv; }
  __syncthreads();
  if (threadIdx.x == 0) {
    mk = fmaxf(fmaxf(redk[0], redk[1]), fmaxf(redk[2], redk[3]));
    mv = fmaxf(fmaxf(redv[0], redv[1]), fmaxf(redv[2], redv[3]));
    atomicMax(amax + 0, __float_as_uint(mk));
    atomicMax(amax + 1, __float_as_uint(mv));
  }
}

__global__ __launch_bounds__(256) void k_quant(const bf16* __restrict__ qkv,
                                               const unsigned int* __restrict__ amax,
                                               float* __restrict__ out) {
  const float ka = __uint_as_float(amax[0]);
  const float va = __uint_as_float(amax[1]);
  const float ks = ka > 0.0f ? ka / 127.0f : 1.0f;
  const float vs = va > 0.0f ? va / 127.0f : 1.0f;
  if (blockIdx.x == 0 && threadIdx.x == 0) { out[OUT_KS] = ks; out[OUT_VS] = vs; }
  const float kinv = 1.0f / ks, vinv = 1.0f / vs;
  const size_t nchunks = 1048576;
  const size_t stride = (size_t)gridDim.x * blockDim.x;
  for (size_t ci = (size_t)blockIdx.x * blockDim.x + threadIdx.x; ci < nchunks; ci += stride) {
    const int d0 = (int)(ci & 7) * 8;
    const int t  = (int)(ci >> 3) & 2047;
    const int h  = (int)(ci >> 14) & 15;
    const int b  = (int)(ci >> 18);
    const size_t src = ((size_t)(b * Tn + t)) * C3n + h * HSn + d0;
    bf16x8 k8 = *(const bf16x8*)(qkv + src + Cn);
    bf16x8 v8 = *(const bf16x8*)(qkv + src + 2 * Cn);
    float kq[8], vq[8];
#pragma unroll
    for (int j = 0; j < 8; ++j) {
      kq[j] = fminf(fmaxf(rintf((float)k8[j] * kinv), -127.0f), 127.0f);
      vq[j] = fminf(fmaxf(rintf((float)v8[j] * vinv), -127.0f), 127.0f);
    }
    const size_t oi = ci * 8;
    f32x4 a0 = {kq[0], kq[1], kq[2], kq[3]};
    f32x4 a1 = {kq[4], kq[5], kq[6], kq[7]};
    *(f32x4*)(out + OUT_KQ + oi)     = a0;
    *(f32x4*)(out + OUT_KQ + oi + 4) = a1;
    float* vdst = out + OUT_VQ + oi;
#pragma unroll
    for (int j = 0; j < 8; ++j) vdst[j] = vq[j];
  }
}

// ============================================================
// MFMA flash attention, causal. Block = (b,h,q-tile of 64). 4 waves x 16 q-rows.
// K-tiles of 64 cols. Q/K staged swizzled via global_load_lds (conflict-free
// b128 frag reads at lead 64); V transposed into Vt[64][72]; P via Ps[64][72].
__global__ __launch_bounds__(256) void k_attn(const bf16* __restrict__ qkv,
                                              bf16* __restrict__ y) {
  __shared__ bf16 Qs[64 * 64];
  __shared__ bf16 Ks[64 * 64];
  __shared__ bf16 Vt[64 * 72];
  __shared__ bf16 Ps[64 * 72];

  const int tid = threadIdx.x;
  const int lane = tid & 63;
  const int w = tid >> 6;
  const int quad = lane >> 4;
  const int l15 = lane & 15;

  const int qt = 31 - (int)blockIdx.x;     // long blocks first
  const int bh = blockIdx.y;
  const int b = bh >> 4, h = bh & 15;
  const int q0 = qt * 64;

  const bf16* qkv_b = qkv + (size_t)b * Tn * C3n + h * HSn;

  // ---- stage Q (swizzled: phys chunk = log chunk ^ (row&7)) ----
#pragma unroll
  for (int j = 0; j < 2; ++j) {
    const int g = w + 4 * j;                  // 8-row group
    const int row = 8 * g + (lane >> 3);
    const int c = (lane & 7) ^ (row & 7);
    g2l16(qkv_b + (size_t)(q0 + row) * C3n + c * 8, Qs + g * 512);
  }
  __builtin_amdgcn_s_waitcnt(0);
  __syncthreads();

  // Q fragments to regs (row = 16w + l15; row&7 == lane&7)
  bf16x8 qf[2];
#pragma unroll
  for (int ks = 0; ks < 2; ++ks) {
    const int row = 16 * w + l15;
    const int c = (ks * 4 + quad) ^ (lane & 7);
    qf[ks] = *(const bf16x8*)(Qs + row * 64 + c * 8);
  }
  __syncthreads();   // Qs reads done (it's not reused, but keep staging clean)

  f32x4 O[4] = {};
  float m_i[4] = {-INFINITY, -INFINITY, -INFINITY, -INFINITY};
  float l_i[4] = {0.0f, 0.0f, 0.0f, 0.0f};

  for (int kt = 0; kt <= qt; ++kt) {
    const int kv0 = kt * 64;

    // stage K (swizzled, async)
#pragma unroll
    for (int j = 0; j < 2; ++j) {
      const int g = w + 4 * j;
      const int row = 8 * g + (lane >> 3);
      const int c = (lane & 7) ^ (row & 7);
      g2l16(qkv_b + Cn + (size_t)(kv0 + row) * C3n + c * 8, Ks + g * 512);
    }
    // stage V transposed: lane kl loads V[kv0+kl][d0..d0+7] for d0 in {8w, 8(w+4)}
    const int kl = lane;
    bf16x8 v0 = *(const bf16x8*)(qkv_b + 2 * Cn + (size_t)(kv0 + kl) * C3n + w * 8);
    bf16x8 v1 = *(const bf16x8*)(qkv_b + 2 * Cn + (size_t)(kv0 + kl) * C3n + (w + 4) * 8);
#pragma unroll
    for (int j = 0; j < 8; ++j) {
      Vt[(w * 8 + j) * 72 + kl]       = v0[j];
      Vt[((w + 4) * 8 + j) * 72 + kl] = v1[j];
    }
    __builtin_amdgcn_s_waitcnt(0);
    __syncthreads();

    // ---- S = Q K^T ----
    f32x4 Sacc[4] = {};
#pragma unroll
    for (int ks = 0; ks < 2; ++ks) {
#pragma unroll
      for (int nt = 0; nt < 4; ++nt) {
        const int rn = nt * 16 + l15;
        const int c = (ks * 4 + quad) ^ (lane & 7);
        bf16x8 kf = *(const bf16x8*)(Ks + rn * 64 + c * 8);
        Sacc[nt] = __builtin_amdgcn_mfma_f32_16x16x32_bf16(qf[ks], kf, Sacc[nt], 0, 0, 0);
      }
    }

    // ---- online softmax (C layout: row = quad*4+rr, col = nt*16+l15) ----
    const bool diag = (kt == qt);
    float alpha[4];
#pragma unroll
    for (int rr = 0; rr < 4; ++rr) {
      const int row = 16 * w + quad * 4 + rr;
      float s[4];
#pragma unroll
      for (int nt = 0; nt < 4; ++nt) {
        const int col = nt * 16 + l15;
        s[nt] = (diag && col > row) ? -INFINITY : Sacc[nt][rr] * 0.125f;
      }
      float mx = fmaxf(fmaxf(s[0], s[1]), fmaxf(s[2], s[3]));
      mx = fmaxf(mx, __shfl_xor(mx, 1));
      mx = fmaxf(mx, __shfl_xor(mx, 2));
      mx = fmaxf(mx, __shfl_xor(mx, 4));
      mx = fmaxf(mx, __shfl_xor(mx, 8));
      const float mn = fmaxf(m_i[rr], mx);
      const float al = __expf(m_i[rr] - mn);
      m_i[rr] = mn;
      float rsum = 0.0f;
#pragma unroll
      for (int nt = 0; nt < 4; ++nt) {
        const float p = __expf(s[nt] - mn);
        rsum += p;
        Ps[row * 72 + nt * 16 + l15] = (bf16)p;
      }
      rsum += __shfl_xor(rsum, 1);
      rsum += __shfl_xor(rsum, 2);
      rsum += __shfl_xor(rsum, 4);
      rsum += __shfl_xor(rsum, 8);
      l_i[rr] = l_i[rr] * al + rsum;
      alpha[rr] = al;
    }
#pragma unroll
    for (int dt = 0; dt < 4; ++dt)
#pragma unroll
      for (int rr = 0; rr < 4; ++rr) O[dt][rr] *= alpha[rr];

    // ---- O += P V  (P rows are wave-private; compiler orders ds_write->ds_read) ----
#pragma unroll
    for (int ks2 = 0; ks2 < 2; ++ks2) {
      bf16x8 pf = *(const bf16x8*)(Ps + (16 * w + l15) * 72 + ks2 * 32 + quad * 8);
#pragma unroll
      for (int dt = 0; dt < 4; ++dt) {
        bf16x8 vf = *(const bf16x8*)(Vt + (dt * 16 + l15) * 72 + ks2 * 32 + quad * 8);
        O[dt] = __builtin_amdgcn_mfma_f32_16x16x32_bf16(pf, vf, O[dt], 0, 0, 0);
      }
    }
    __syncthreads();   // Ks/Vt consumed before next iter restages
  }

  // ---- write y (B,T,C) ----
#pragma unroll
  for (int rr = 0; rr < 4; ++rr) {
    const int row = 16 * w + quad * 4 + rr;
    const float invl = 1.0f / l_i[rr];
    const size_t yb = ((size_t)b * Tn + q0 + row) * Cn + h * HSn;
#pragma unroll
    for (int dt = 0; dt < 4; ++dt)
      y[yb + dt * 16 + l15] = (bf16)(O[dt][rr] * invl);
  }
}

// ============================================================
extern "C" void kernel_launch(void* const* d_in, const int* in_sizes, int n_in,
                              void* d_out, int out_size, void* d_ws, size_t ws_size,
                              hipStream_t stream) {
  const float* x     = (const float*)d_in[0];
  const float* ln1w  = (const float*)d_in[1];
  const float* ln1b  = (const float*)d_in[2];
  const float* Wqkv  = (const float*)d_in[3];
  const float* bqkv  = (const float*)d_in[4];
  const float* Wo    = (const float*)d_in[5];
  const float* bo    = (const float*)d_in[6];
  const float* ln2w  = (const float*)d_in[7];
  const float* ln2b  = (const float*)d_in[8];
  const float* Wfc   = (const float*)d_in[9];
  const float* bfc   = (const float*)d_in[10];
  const float* Wpr   = (const float*)d_in[11];
  const float* bpr   = (const float*)d_in[12];

  char* ws = (char*)d_ws;
  bf16*  Wt_qkv = (bf16*)(ws + OFF_WT_QKV);
  bf16*  Wt_o   = (bf16*)(ws + OFF_WT_O);
  bf16*  Wt_fc  = (bf16*)(ws + OFF_WT_FC);
  bf16*  Wt_pr  = (bf16*)(ws + OFF_WT_PR);
  bf16*  h      = (bf16*)(ws + OFF_H);
  bf16*  ybf    = (bf16*)(ws + OFF_Y);
  float* x1     = (float*)(ws + OFF_X1);
  unsigned int* amax = (unsigned int*)(ws + OFF_AMAX);
  bf16*  qkvbf  = (bf16*)(ws + OFF_QKV);
  bf16*  g      = (bf16*)(ws + OFF_G);
  float* out    = (float*)d_out;

  const dim3 tb(32, 8);
  k_transpose<<<dim3(96, 32),  tb, 0, stream>>>(Wqkv, Wt_qkv, 1024, 3072);
  k_transpose<<<dim3(32, 32),  tb, 0, stream>>>(Wo,   Wt_o,   1024, 1024);
  k_transpose<<<dim3(128, 32), tb, 0, stream>>>(Wfc,  Wt_fc,  1024, 4096);
  k_transpose<<<dim3(32, 128), tb, 0, stream>>>(Wpr,  Wt_pr,  4096, 1024);
  k_init<<<1, 64, 0, stream>>>(amax);

  k_ln<<<BTn, 256, 0, stream>>>(x, ln1w, ln1b, h);
  k_gemm<true, false, false><<<dim3(64, 24), 256, 0, stream>>>(h, Wt_qkv, bqkv, nullptr, qkvbf, 8192, 3072, 1024);
  k_absmax<<<1024, 256, 0, stream>>>(qkvbf, amax);
  k_quant<<<2048, 256, 0, stream>>>(qkvbf, amax, out);
  k_attn<<<dim3(32, 64), 256, 0, stream>>>(qkvbf, ybf);
  k_gemm<false, true, false><<<dim3(64, 8), 256, 0, stream>>>(ybf, Wt_o, bo, x, x1, 8192, 1024, 1024);
  k_ln<<<BTn, 256, 0, stream>>>(x1, ln2w, ln2b, h);
  k_gemm<true, false, true><<<dim3(64, 32), 256, 0, stream>>>(h, Wt_fc, bfc, nullptr, g, 8192, 4096, 1024);
  k_gemm<false, true, false><<<dim3(64, 8), 256, 0, stream>>>(g, Wt_pr, bpr, x1, out, 8192, 1024, 4096);
}

// Round 3
// 709.442 us; speedup vs baseline: 3.7565x; 1.1261x over previous
//
#include <hip/hip_runtime.h>
#include <cmath>

typedef __bf16 bf16;
typedef float f32x4 __attribute__((ext_vector_type(4)));
typedef __bf16 bf16x4 __attribute__((ext_vector_type(4)));
typedef __bf16 bf16x8 __attribute__((ext_vector_type(8)));

#define DEVI __device__ __forceinline__

// ---- problem dims ----
constexpr int Bn = 4, Tn = 2048, Cn = 1024, Hn = 16, HSn = 64;
constexpr int C3n = 3 * Cn;      // 3072
constexpr int BTn = Bn * Tn;     // 8192

// ---- workspace layout (bytes) ----
constexpr size_t OFF_WT_QKV = 0;           // 3072x1024 bf16
constexpr size_t OFF_WT_O   = 6291456;     // 1024x1024 bf16
constexpr size_t OFF_WT_FC  = 8388608;     // 4096x1024 bf16
constexpr size_t OFF_WT_PR  = 16777216;    // 1024x4096 bf16
constexpr size_t OFF_H      = 25165824;    // 8192x1024 bf16 (h / h2)
constexpr size_t OFF_Y      = 41943040;    // 8192x1024 bf16 (attn out)
constexpr size_t OFF_X1     = 58720256;    // 8192x1024 f32  (resid1)
constexpr size_t OFF_AMAX   = 92274688;    // 2 x u32
constexpr size_t OFF_QKV    = 92274944;    // 8192x3072 bf16
constexpr size_t OFF_G      = OFF_QKV;     // 8192x4096 bf16 (aliases qkv, dead by then)

// ---- d_out layout (float elements) ----
constexpr size_t OUT_X  = 0;          // (B,T,C)
constexpr size_t OUT_KQ = 8388608;    // (B,H,T,HS)
constexpr size_t OUT_KS = 16777216;   // scalar
constexpr size_t OUT_VQ = 16777217;   // (B,H,T,HS)
constexpr size_t OUT_VS = 25165825;   // scalar

// ============================================================
DEVI void g2l16(const void* g, void* l) {
  __builtin_amdgcn_global_load_lds(
      (__attribute__((address_space(1))) void*)g,
      (__attribute__((address_space(3))) void*)l, 16, 0, 0);
}

// ============================================================
// transpose + cast: W (K x N) f32 -> Wt (N x K) bf16
__global__ __launch_bounds__(256) void k_transpose(const float* __restrict__ W,
                                                   bf16* __restrict__ Wt,
                                                   int K, int N) {
  __shared__ float tile[32][33];
  const int n0 = blockIdx.x * 32, k0 = blockIdx.y * 32;
  const int tx = threadIdx.x, ty = threadIdx.y;   // block (32,8)
#pragma unroll
  for (int i = 0; i < 4; ++i) {
    int k = k0 + ty + i * 8;
    tile[ty + i * 8][tx] = W[(size_t)k * N + (n0 + tx)];
  }
  __syncthreads();
#pragma unroll
  for (int i = 0; i < 4; ++i) {
    int n = n0 + ty + i * 8;
    Wt[(size_t)n * K + (k0 + tx)] = (bf16)tile[tx][ty + i * 8];
  }
}

// ============================================================
// LayerNorm row of 1024, f32 in -> bf16 out.
__global__ __launch_bounds__(256) void k_ln(const float* __restrict__ x,
                                            const float* __restrict__ g,
                                            const float* __restrict__ b,
                                            bf16* __restrict__ out) {
  __shared__ float red[8];
  const int row = blockIdx.x, tid = threadIdx.x;
  const int lane = tid & 63, wv = tid >> 6;
  f32x4 v = ((const f32x4*)(x + (size_t)row * Cn))[tid];

  float s = v[0] + v[1] + v[2] + v[3];
  s += __shfl_down(s, 32); s += __shfl_down(s, 16); s += __shfl_down(s, 8);
  s += __shfl_down(s, 4);  s += __shfl_down(s, 2);  s += __shfl_down(s, 1);
  if (!lane) red[wv] = s;
  __syncthreads();
  const float mean = (red[0] + red[1] + red[2] + red[3]) * (1.0f / 1024.0f);
  __syncthreads();

  f32x4 d = v - mean;
  float s2 = d[0]*d[0] + d[1]*d[1] + d[2]*d[2] + d[3]*d[3];
  s2 += __shfl_down(s2, 32); s2 += __shfl_down(s2, 16); s2 += __shfl_down(s2, 8);
  s2 += __shfl_down(s2, 4);  s2 += __shfl_down(s2, 2);  s2 += __shfl_down(s2, 1);
  if (!lane) red[wv] = s2;
  __syncthreads();
  const float var = (red[0] + red[1] + red[2] + red[3]) * (1.0f / 1024.0f);
  const float inv = rsqrtf(var + 1e-5f);

  f32x4 gw = ((const f32x4*)g)[tid];
  f32x4 bb = ((const f32x4*)b)[tid];
  bf16x4 o;
#pragma unroll
  for (int j = 0; j < 4; ++j) o[j] = (bf16)(d[j] * inv * gw[j] + bb[j]);
  *(bf16x4*)(out + (size_t)row * Cn + tid * 4) = o;
}

// ============================================================
// MFMA GEMM: C(MxN) = A(MxK,bf16) * Bt(NxK,bf16)^T + bias [+GELU] [+res]
template <bool BF16OUT, bool RES, bool GELU>
__global__ __launch_bounds__(256) void k_gemm(const bf16* __restrict__ A,
                                              const bf16* __restrict__ Bt,
                                              const float* __restrict__ bias,
                                              const float* __restrict__ res,
                                              void* __restrict__ Cout,
                                              int M, int N, int K) {
  __shared__ bf16 As[128 * 32];
  __shared__ bf16 Bs[128 * 32];
  const int tid = threadIdx.x;
  const int lane = tid & 63;
  const int w = tid >> 6;
  const int wm = w & 1, wn = w >> 1;
  const int m0 = blockIdx.x * 128, n0 = blockIdx.y * 128;

  const bf16* aSrc = A  + (size_t)(m0 + (tid >> 2)) * K + (tid & 3) * 8;
  const bf16* bSrc = Bt + (size_t)(n0 + (tid >> 2)) * K + (tid & 3) * 8;
  bf16* aDst = As + 512 * w;
  bf16* bDst = Bs + 512 * w;

  const bf16* aFrag = As + (wm * 64 + (lane & 15)) * 32 + (lane >> 4) * 8;
  const bf16* bFrag = Bs + (wn * 64 + (lane & 15)) * 32 + (lane >> 4) * 8;

  f32x4 acc[4][4] = {};
  const int kIters = K >> 5;
  for (int kt = 0; kt < kIters; ++kt) {
    g2l16(aSrc, aDst);
    g2l16(aSrc + (size_t)64 * K, aDst + 2048);
    g2l16(bSrc, bDst);
    g2l16(bSrc + (size_t)64 * K, bDst + 2048);
    aSrc += 32; bSrc += 32;
    __builtin_amdgcn_s_waitcnt(0);
    __syncthreads();

    bf16x8 af[4], bv[4];
#pragma unroll
    for (int mt = 0; mt < 4; ++mt) af[mt] = *(const bf16x8*)(aFrag + mt * 512);
#pragma unroll
    for (int nt = 0; nt < 4; ++nt) bv[nt] = *(const bf16x8*)(bFrag + nt * 512);
#pragma unroll
    for (int mt = 0; mt < 4; ++mt)
#pragma unroll
      for (int nt = 0; nt < 4; ++nt)
        acc[mt][nt] = __builtin_amdgcn_mfma_f32_16x16x32_bf16(af[mt], bv[nt], acc[mt][nt], 0, 0, 0);
    __syncthreads();
  }

  const int colB = n0 + wn * 64 + (lane & 15);
  const int rowB = m0 + wm * 64 + ((lane >> 4) << 2);
#pragma unroll
  for (int mt = 0; mt < 4; ++mt) {
#pragma unroll
    for (int nt = 0; nt < 4; ++nt) {
      const int col = colB + nt * 16;
      const float bval = bias[col];
#pragma unroll
      for (int r = 0; r < 4; ++r) {
        const int row = rowB + mt * 16 + r;
        float val = acc[mt][nt][r] + bval;
        if (GELU) val = 0.5f * val * (1.0f + erff(val * 0.7071067811865476f));
        if (RES)  val += res[(size_t)row * N + col];
        if (BF16OUT) ((bf16*)Cout)[(size_t)row * N + col] = (bf16)val;
        else         ((float*)Cout)[(size_t)row * N + col] = val;
      }
    }
  }
}

// ============================================================
__global__ __launch_bounds__(256) void k_init(unsigned int* amax) {
  if (threadIdx.x < 2) amax[threadIdx.x] = 0u;
}

__global__ __launch_bounds__(256) void k_absmax(const bf16* __restrict__ qkv,
                                                unsigned int* __restrict__ amax) {
  __shared__ float redk[4], redv[4];
  float mk = 0.0f, mv = 0.0f;
  const size_t nchunks = (size_t)BTn * 128;
  const size_t stride = (size_t)gridDim.x * blockDim.x;
  for (size_t ci = (size_t)blockIdx.x * blockDim.x + threadIdx.x; ci < nchunks; ci += stride) {
    const size_t bt = ci >> 7;
    const int c8 = (int)(ci & 127) * 8;
    const bf16* base = qkv + bt * C3n + c8;
    bf16x8 k8 = *(const bf16x8*)(base + Cn);
    bf16x8 v8 = *(const bf16x8*)(base + 2 * Cn);
#pragma unroll
    for (int j = 0; j < 8; ++j) {
      mk = fmaxf(mk, fabsf((float)k8[j]));
      mv = fmaxf(mv, fabsf((float)v8[j]));
    }
  }
  for (int off = 32; off; off >>= 1) {
    mk = fmaxf(mk, __shfl_down(mk, off));
    mv = fmaxf(mv, __shfl_down(mv, off));
  }
  const int lane = threadIdx.x & 63, wv = threadIdx.x >> 6;
  if (!lane) { redk[wv] = mk; redv[wv] = mv; }
  __syncthreads();
  if (threadIdx.x == 0) {
    mk = fmaxf(fmaxf(redk[0], redk[1]), fmaxf(redk[2], redk[3]));
    mv = fmaxf(fmaxf(redv[0], redv[1]), fmaxf(redv[2], redv[3]));
    atomicMax(amax + 0, __float_as_uint(mk));
    atomicMax(amax + 1, __float_as_uint(mv));
  }
}

__global__ __launch_bounds__(256) void k_quant(const bf16* __restrict__ qkv,
                                               const unsigned int* __restrict__ amax,
                                               float* __restrict__ out) {
  const float ka = __uint_as_float(amax[0]);
  const float va = __uint_as_float(amax[1]);
  const float ks = ka > 0.0f ? ka / 127.0f : 1.0f;
  const float vs = va > 0.0f ? va / 127.0f : 1.0f;
  if (blockIdx.x == 0 && threadIdx.x == 0) { out[OUT_KS] = ks; out[OUT_VS] = vs; }
  const float kinv = 1.0f / ks, vinv = 1.0f / vs;
  const size_t nchunks = 1048576;
  const size_t stride = (size_t)gridDim.x * blockDim.x;
  for (size_t ci = (size_t)blockIdx.x * blockDim.x + threadIdx.x; ci < nchunks; ci += stride) {
    const int d0 = (int)(ci & 7) * 8;
    const int t  = (int)(ci >> 3) & 2047;
    const int h  = (int)(ci >> 14) & 15;
    const int b  = (int)(ci >> 18);
    const size_t src = ((size_t)(b * Tn + t)) * C3n + h * HSn + d0;
    bf16x8 k8 = *(const bf16x8*)(qkv + src + Cn);
    bf16x8 v8 = *(const bf16x8*)(qkv + src + 2 * Cn);
    float kq[8], vq[8];
#pragma unroll
    for (int j = 0; j < 8; ++j) {
      kq[j] = fminf(fmaxf(rintf((float)k8[j] * kinv), -127.0f), 127.0f);
      vq[j] = fminf(fmaxf(rintf((float)v8[j] * vinv), -127.0f), 127.0f);
    }
    const size_t oi = ci * 8;
    f32x4 a0 = {kq[0], kq[1], kq[2], kq[3]};
    f32x4 a1 = {kq[4], kq[5], kq[6], kq[7]};
    *(f32x4*)(out + OUT_KQ + oi)     = a0;
    *(f32x4*)(out + OUT_KQ + oi + 4) = a1;
    float* vdst = out + OUT_VQ + oi;
#pragma unroll
    for (int j = 0; j < 8; ++j) vdst[j] = vq[j];
  }
}

// ============================================================
// Transposed-score MFMA flash attention, causal.
// Block = (b,h,q-tile of 64), 4 waves x 16 q. S^T = K*Q^T so C-layout col
// (lane&15) = q: softmax state is a lane scalar, reductions are 2 shuffles.
// O^T = V^T * P^T accumulated in C-layout (rows = d, col = q).
__global__ __launch_bounds__(256) void k_attn(const bf16* __restrict__ qkv,
                                              bf16* __restrict__ y) {
  __shared__ bf16 Qs[64 * 64];
  __shared__ bf16 Ks[64 * 64];
  __shared__ bf16 Vt[64 * 72];
  __shared__ bf16 Pt[4 * 16 * 72];

  const int tid = threadIdx.x;
  const int lane = tid & 63;
  const int w = tid >> 6;
  const int quad = lane >> 4;
  const int l15 = lane & 15;

  const int qt = 31 - (int)blockIdx.x;     // long blocks first
  const int bh = blockIdx.y;
  const int b = bh >> 4, h = bh & 15;
  const int q0 = qt * 64;

  const bf16* qkv_b = qkv + (size_t)b * Tn * C3n + h * HSn;
  bf16* Pw = Pt + w * (16 * 72);

  // ---- stage Q (swizzled: phys chunk = log chunk ^ (row&7)) ----
#pragma unroll
  for (int j = 0; j < 2; ++j) {
    const int g = w + 4 * j;                  // 8-row group
    const int row = 8 * g + (lane >> 3);
    const int c = (lane & 7) ^ (row & 7);
    g2l16(qkv_b + (size_t)(q0 + row) * C3n + c * 8, Qs + g * 512);
  }
  __builtin_amdgcn_s_waitcnt(0);
  __syncthreads();

  // Q fragments (B-operand): n = q = 16w + l15, k = quad*8+j (+32ks)
  bf16x8 qf[2];
#pragma unroll
  for (int ks = 0; ks < 2; ++ks) {
    const int row = 16 * w + l15;
    const int c = (ks * 4 + quad) ^ (row & 7);
    qf[ks] = *(const bf16x8*)(Qs + row * 64 + c * 8);
  }

  f32x4 Od[4] = {};
  float m_i = -INFINITY, l_i = 0.0f;

  // prefetch V tile 0
  bf16x8 v0 = *(const bf16x8*)(qkv_b + 2 * Cn + (size_t)lane * C3n + w * 8);
  bf16x8 v1 = *(const bf16x8*)(qkv_b + 2 * Cn + (size_t)lane * C3n + (w + 4) * 8);

  for (int kt = 0; kt <= qt; ++kt) {
    const int kv0 = kt * 64;

    // stage K (swizzled, async)
#pragma unroll
    for (int j = 0; j < 2; ++j) {
      const int g = w + 4 * j;
      const int row = 8 * g + (lane >> 3);
      const int c = (lane & 7) ^ (row & 7);
      g2l16(qkv_b + Cn + (size_t)(kv0 + row) * C3n + c * 8, Ks + g * 512);
    }
    // prefetch next V tile (latency hidden behind compute)
    bf16x8 v0n, v1n;
    if (kt < qt) {
      const bf16* vsrc = qkv_b + 2 * Cn + (size_t)(kv0 + 64 + lane) * C3n;
      v0n = *(const bf16x8*)(vsrc + w * 8);
      v1n = *(const bf16x8*)(vsrc + (w + 4) * 8);
    }
    // write current V transposed: Vt[d][kc], d = 8w+j / 8(w+4)+j, kc = lane
#pragma unroll
    for (int j = 0; j < 8; ++j) {
      Vt[(w * 8 + j) * 72 + lane]       = v0[j];
      Vt[((w + 4) * 8 + j) * 72 + lane] = v1[j];
    }
    __builtin_amdgcn_s_waitcnt(0);
    __syncthreads();

    // ---- S^T = K Q^T : D[m=kc][n=q] ----
    f32x4 Sacc[4] = {};
#pragma unroll
    for (int ks = 0; ks < 2; ++ks) {
#pragma unroll
      for (int nt = 0; nt < 4; ++nt) {
        const int rn = nt * 16 + l15;            // kc row
        const int c = (ks * 4 + quad) ^ (rn & 7);
        bf16x8 kf = *(const bf16x8*)(Ks + rn * 64 + c * 8);
        Sacc[nt] = __builtin_amdgcn_mfma_f32_16x16x32_bf16(kf, qf[ks], Sacc[nt], 0, 0, 0);
      }
    }

    // ---- online softmax: lane owns q = 16w+l15, 16 kc values ----
    const bool diag = (kt == qt);
    const int qrow = 16 * w + l15;
    float s[4][4];
    float mx = -INFINITY;
#pragma unroll
    for (int nt = 0; nt < 4; ++nt)
#pragma unroll
      for (int r = 0; r < 4; ++r) {
        float v = Sacc[nt][r] * 0.125f;
        if (diag && (nt * 16 + quad * 4 + r > qrow)) v = -INFINITY;
        s[nt][r] = v;
        mx = fmaxf(mx, v);
      }
    mx = fmaxf(mx, __shfl_xor(mx, 16));
    mx = fmaxf(mx, __shfl_xor(mx, 32));
    const float mn = fmaxf(m_i, mx);
    const float al = __expf(m_i - mn);
    m_i = mn;
    float rsum = 0.0f;
    bf16x4 pk[4];
#pragma unroll
    for (int nt = 0; nt < 4; ++nt)
#pragma unroll
      for (int r = 0; r < 4; ++r) {
        const float p = __expf(s[nt][r] - mn);
        rsum += p;
        pk[nt][r] = (bf16)p;
      }
    rsum += __shfl_xor(rsum, 16);
    rsum += __shfl_xor(rsum, 32);
    l_i = l_i * al + rsum;
#pragma unroll
    for (int dt = 0; dt < 4; ++dt) Od[dt] *= al;
    // P^T pack: 4 consecutive kc per reg quad -> b64 writes (wave-private Pw)
#pragma unroll
    for (int nt = 0; nt < 4; ++nt)
      *(bf16x4*)(Pw + l15 * 72 + nt * 16 + quad * 4) = pk[nt];

    // ---- O^T += V^T P^T : A = Vt rows (d), B = Pt rows (q) ----
#pragma unroll
    for (int ks2 = 0; ks2 < 2; ++ks2) {
      bf16x8 pf = *(const bf16x8*)(Pw + l15 * 72 + ks2 * 32 + quad * 8);
#pragma unroll
      for (int dt = 0; dt < 4; ++dt) {
        bf16x8 vf = *(const bf16x8*)(Vt + (dt * 16 + l15) * 72 + ks2 * 32 + quad * 8);
        Od[dt] = __builtin_amdgcn_mfma_f32_16x16x32_bf16(vf, pf, Od[dt], 0, 0, 0);
      }
    }
    v0 = v0n; v1 = v1n;
    __syncthreads();   // Ks/Vt consumed before next restage
  }

  // ---- write y (B,T,C): lane owns q; d = dt*16 + quad*4 + r contiguous ----
  const float invl = 1.0f / l_i;
  const size_t yb = ((size_t)b * Tn + q0 + 16 * w + l15) * Cn + h * HSn;
#pragma unroll
  for (int dt = 0; dt < 4; ++dt) {
    bf16x4 o;
#pragma unroll
    for (int r = 0; r < 4; ++r) o[r] = (bf16)(Od[dt][r] * invl);
    *(bf16x4*)(y + yb + dt * 16 + quad * 4) = o;
  }
}

// ============================================================
extern "C" void kernel_launch(void* const* d_in, const int* in_sizes, int n_in,
                              void* d_out, int out_size, void* d_ws, size_t ws_size,
                              hipStream_t stream) {
  const float* x     = (const float*)d_in[0];
  const float* ln1w  = (const float*)d_in[1];
  const float* ln1b  = (const float*)d_in[2];
  const float* Wqkv  = (const float*)d_in[3];
  const float* bqkv  = (const float*)d_in[4];
  const float* Wo    = (const float*)d_in[5];
  const float* bo    = (const float*)d_in[6];
  const float* ln2w  = (const float*)d_in[7];
  const float* ln2b  = (const float*)d_in[8];
  const float* Wfc   = (const float*)d_in[9];
  const float* bfc   = (const float*)d_in[10];
  const float* Wpr   = (const float*)d_in[11];
  const float* bpr   = (const float*)d_in[12];

  char* ws = (char*)d_ws;
  bf16*  Wt_qkv = (bf16*)(ws + OFF_WT_QKV);
  bf16*  Wt_o   = (bf16*)(ws + OFF_WT_O);
  bf16*  Wt_fc  = (bf16*)(ws + OFF_WT_FC);
  bf16*  Wt_pr  = (bf16*)(ws + OFF_WT_PR);
  bf16*  h      = (bf16*)(ws + OFF_H);
  bf16*  ybf    = (bf16*)(ws + OFF_Y);
  float* x1     = (float*)(ws + OFF_X1);
  unsigned int* amax = (unsigned int*)(ws + OFF_AMAX);
  bf16*  qkvbf  = (bf16*)(ws + OFF_QKV);
  bf16*  g      = (bf16*)(ws + OFF_G);
  float* out    = (float*)d_out;

  const dim3 tb(32, 8);
  k_transpose<<<dim3(96, 32),  tb, 0, stream>>>(Wqkv, Wt_qkv, 1024, 3072);
  k_transpose<<<dim3(32, 32),  tb, 0, stream>>>(Wo,   Wt_o,   1024, 1024);
  k_transpose<<<dim3(128, 32), tb, 0, stream>>>(Wfc,  Wt_fc,  1024, 4096);
  k_transpose<<<dim3(32, 128), tb, 0, stream>>>(Wpr,  Wt_pr,  4096, 1024);
  k_init<<<1, 64, 0, stream>>>(amax);

  k_ln<<<BTn, 256, 0, stream>>>(x, ln1w, ln1b, h);
  k_gemm<true, false, false><<<dim3(64, 24), 256, 0, stream>>>(h, Wt_qkv, bqkv, nullptr, qkvbf, 8192, 3072, 1024);
  k_absmax<<<1024, 256, 0, stream>>>(qkvbf, amax);
  k_quant<<<2048, 256, 0, stream>>>(qkvbf, amax, out);
  k_attn<<<dim3(32, 64), 256, 0, stream>>>(qkvbf, ybf);
  k_gemm<false, true, false><<<dim3(64, 8), 256, 0, stream>>>(ybf, Wt_o, bo, x, x1, 8192, 1024, 1024);
  k_ln<<<BTn, 256, 0, stream>>>(x1, ln2w, ln2b, h);
  k_gemm<true, false, true><<<dim3(64, 32), 256, 0, stream>>>(h, Wt_fc, bfc, nullptr, g, 8192, 4096, 1024);
  k_gemm<false, true, false><<<dim3(64, 8), 256, 0, stream>>>(g, Wt_pr, bpr, x1, out, 8192, 1024, 4096);
}

// Round 4
// 682.294 us; speedup vs baseline: 3.9060x; 1.0398x over previous
//
#include <hip/hip_runtime.h>
#include <cmath>

typedef __bf16 bf16;
typedef float f32x4 __attribute__((ext_vector_type(4)));
typedef __bf16 bf16x4 __attribute__((ext_vector_type(4)));
typedef __bf16 bf16x8 __attribute__((ext_vector_type(8)));

#define DEVI __device__ __forceinline__

// ---- problem dims ----
constexpr int Bn = 4, Tn = 2048, Cn = 1024, Hn = 16, HSn = 64;
constexpr int C3n = 3 * Cn;      // 3072
constexpr int BTn = Bn * Tn;     // 8192

// ---- workspace layout (bytes) ----
constexpr size_t OFF_WT_QKV = 0;           // 3072x1024 bf16
constexpr size_t OFF_WT_O   = 6291456;     // 1024x1024 bf16
constexpr size_t OFF_WT_FC  = 8388608;     // 4096x1024 bf16
constexpr size_t OFF_WT_PR  = 16777216;    // 1024x4096 bf16
constexpr size_t OFF_H      = 25165824;    // 8192x1024 bf16 (h / h2)
constexpr size_t OFF_Y      = 41943040;    // 8192x1024 bf16 (attn out)
constexpr size_t OFF_X1     = 58720256;    // 8192x1024 f32  (resid1)
constexpr size_t OFF_AMAX   = 92274688;    // 2 x u32
constexpr size_t OFF_QKV    = 92274944;    // 8192x3072 bf16
constexpr size_t OFF_G      = OFF_QKV;     // 8192x4096 bf16 (aliases qkv, dead by then)

// ---- d_out layout (float elements) ----
constexpr size_t OUT_X  = 0;          // (B,T,C)
constexpr size_t OUT_KQ = 8388608;    // (B,H,T,HS)
constexpr size_t OUT_KS = 16777216;   // scalar
constexpr size_t OUT_VQ = 16777217;   // (B,H,T,HS)
constexpr size_t OUT_VS = 25165825;   // scalar

// ============================================================
DEVI void g2l16(const void* g, void* l) {
  __builtin_amdgcn_global_load_lds(
      (__attribute__((address_space(1))) void*)g,
      (__attribute__((address_space(3))) void*)l, 16, 0, 0);
}

// ============================================================
// transpose + cast: W (K x N) f32 -> Wt (N x K) bf16
__global__ __launch_bounds__(256) void k_transpose(const float* __restrict__ W,
                                                   bf16* __restrict__ Wt,
                                                   int K, int N) {
  __shared__ float tile[32][33];
  const int n0 = blockIdx.x * 32, k0 = blockIdx.y * 32;
  const int tx = threadIdx.x, ty = threadIdx.y;   // block (32,8)
#pragma unroll
  for (int i = 0; i < 4; ++i) {
    int k = k0 + ty + i * 8;
    tile[ty + i * 8][tx] = W[(size_t)k * N + (n0 + tx)];
  }
  __syncthreads();
#pragma unroll
  for (int i = 0; i < 4; ++i) {
    int n = n0 + ty + i * 8;
    Wt[(size_t)n * K + (k0 + tx)] = (bf16)tile[tx][ty + i * 8];
  }
}

// ============================================================
// LayerNorm row of 1024, f32 in -> bf16 out.
__global__ __launch_bounds__(256) void k_ln(const float* __restrict__ x,
                                            const float* __restrict__ g,
                                            const float* __restrict__ b,
                                            bf16* __restrict__ out) {
  __shared__ float red[8];
  const int row = blockIdx.x, tid = threadIdx.x;
  const int lane = tid & 63, wv = tid >> 6;
  f32x4 v = ((const f32x4*)(x + (size_t)row * Cn))[tid];

  float s = v[0] + v[1] + v[2] + v[3];
  s += __shfl_down(s, 32); s += __shfl_down(s, 16); s += __shfl_down(s, 8);
  s += __shfl_down(s, 4);  s += __shfl_down(s, 2);  s += __shfl_down(s, 1);
  if (!lane) red[wv] = s;
  __syncthreads();
  const float mean = (red[0] + red[1] + red[2] + red[3]) * (1.0f / 1024.0f);
  __syncthreads();

  f32x4 d = v - mean;
  float s2 = d[0]*d[0] + d[1]*d[1] + d[2]*d[2] + d[3]*d[3];
  s2 += __shfl_down(s2, 32); s2 += __shfl_down(s2, 16); s2 += __shfl_down(s2, 8);
  s2 += __shfl_down(s2, 4);  s2 += __shfl_down(s2, 2);  s2 += __shfl_down(s2, 1);
  if (!lane) red[wv] = s2;
  __syncthreads();
  const float var = (red[0] + red[1] + red[2] + red[3]) * (1.0f / 1024.0f);
  const float inv = rsqrtf(var + 1e-5f);

  f32x4 gw = ((const f32x4*)g)[tid];
  f32x4 bb = ((const f32x4*)b)[tid];
  bf16x4 o;
#pragma unroll
  for (int j = 0; j < 4; ++j) o[j] = (bf16)(d[j] * inv * gw[j] + bb[j]);
  *(bf16x4*)(out + (size_t)row * Cn + tid * 4) = o;
}

// ============================================================
// MFMA GEMM: C(MxN) = A(MxK,bf16) * Bt(NxK,bf16)^T + bias [+GELU] [+res] [+absmax]
template <bool BF16OUT, bool RES, bool GELU, bool AMAX>
__global__ __launch_bounds__(256) void k_gemm(const bf16* __restrict__ A,
                                              const bf16* __restrict__ Bt,
                                              const float* __restrict__ bias,
                                              const float* __restrict__ res,
                                              void* __restrict__ Cout,
                                              unsigned int* __restrict__ amax,
                                              int M, int N, int K) {
  __shared__ bf16 As[128 * 32];
  __shared__ bf16 Bs[128 * 32];
  __shared__ float redA[4];
  const int tid = threadIdx.x;
  const int lane = tid & 63;
  const int w = tid >> 6;
  const int wm = w & 1, wn = w >> 1;
  const int m0 = blockIdx.x * 128, n0 = blockIdx.y * 128;

  const bf16* aSrc = A  + (size_t)(m0 + (tid >> 2)) * K + (tid & 3) * 8;
  const bf16* bSrc = Bt + (size_t)(n0 + (tid >> 2)) * K + (tid & 3) * 8;
  bf16* aDst = As + 512 * w;
  bf16* bDst = Bs + 512 * w;

  const bf16* aFrag = As + (wm * 64 + (lane & 15)) * 32 + (lane >> 4) * 8;
  const bf16* bFrag = Bs + (wn * 64 + (lane & 15)) * 32 + (lane >> 4) * 8;

  f32x4 acc[4][4] = {};
  const int kIters = K >> 5;
  for (int kt = 0; kt < kIters; ++kt) {
    g2l16(aSrc, aDst);
    g2l16(aSrc + (size_t)64 * K, aDst + 2048);
    g2l16(bSrc, bDst);
    g2l16(bSrc + (size_t)64 * K, bDst + 2048);
    aSrc += 32; bSrc += 32;
    __builtin_amdgcn_s_waitcnt(0);
    __syncthreads();

    bf16x8 af[4], bv[4];
#pragma unroll
    for (int mt = 0; mt < 4; ++mt) af[mt] = *(const bf16x8*)(aFrag + mt * 512);
#pragma unroll
    for (int nt = 0; nt < 4; ++nt) bv[nt] = *(const bf16x8*)(bFrag + nt * 512);
#pragma unroll
    for (int mt = 0; mt < 4; ++mt)
#pragma unroll
      for (int nt = 0; nt < 4; ++nt)
        acc[mt][nt] = __builtin_amdgcn_mfma_f32_16x16x32_bf16(af[mt], bv[nt], acc[mt][nt], 0, 0, 0);
    __syncthreads();
  }

  const int colB = n0 + wn * 64 + (lane & 15);
  const int rowB = m0 + wm * 64 + ((lane >> 4) << 2);
  float lm = 0.0f;
#pragma unroll
  for (int mt = 0; mt < 4; ++mt) {
#pragma unroll
    for (int nt = 0; nt < 4; ++nt) {
      const int col = colB + nt * 16;
      const float bval = bias[col];
#pragma unroll
      for (int r = 0; r < 4; ++r) {
        const int row = rowB + mt * 16 + r;
        float val = acc[mt][nt][r] + bval;
        if (GELU) val = 0.5f * val * (1.0f + erff(val * 0.7071067811865476f));
        if (RES)  val += res[(size_t)row * N + col];
        if (AMAX) lm = fmaxf(lm, fabsf(val));
        if (BF16OUT) ((bf16*)Cout)[(size_t)row * N + col] = (bf16)val;
        else         ((float*)Cout)[(size_t)row * N + col] = val;
      }
    }
  }

  if (AMAX) {
    const int cls = n0 >> 10;   // 0=Q, 1=K, 2=V (128-tiles never straddle 1024 bounds)
    if (cls > 0) {
      lm = fmaxf(lm, __shfl_xor(lm, 1));
      lm = fmaxf(lm, __shfl_xor(lm, 2));
      lm = fmaxf(lm, __shfl_xor(lm, 4));
      lm = fmaxf(lm, __shfl_xor(lm, 8));
      lm = fmaxf(lm, __shfl_xor(lm, 16));
      lm = fmaxf(lm, __shfl_xor(lm, 32));
      if (!lane) redA[w] = lm;
      __syncthreads();
      if (tid == 0) {
        const float m4 = fmaxf(fmaxf(redA[0], redA[1]), fmaxf(redA[2], redA[3]));
        atomicMax(amax + (cls - 1), __float_as_uint(m4));  // nonneg: uint order == float order
      }
    }
  }
}

// ============================================================
__global__ __launch_bounds__(256) void k_init(unsigned int* amax) {
  if (threadIdx.x < 2) amax[threadIdx.x] = 0u;
}

__global__ __launch_bounds__(256) void k_quant(const bf16* __restrict__ qkv,
                                               const unsigned int* __restrict__ amax,
                                               float* __restrict__ out) {
  const float ka = __uint_as_float(amax[0]);
  const float va = __uint_as_float(amax[1]);
  const float ks = ka > 0.0f ? ka / 127.0f : 1.0f;
  const float vs = va > 0.0f ? va / 127.0f : 1.0f;
  if (blockIdx.x == 0 && threadIdx.x == 0) { out[OUT_KS] = ks; out[OUT_VS] = vs; }
  const float kinv = 1.0f / ks, vinv = 1.0f / vs;
  const size_t nchunks = 1048576;
  const size_t stride = (size_t)gridDim.x * blockDim.x;
  for (size_t ci = (size_t)blockIdx.x * blockDim.x + threadIdx.x; ci < nchunks; ci += stride) {
    const int d0 = (int)(ci & 7) * 8;
    const int t  = (int)(ci >> 3) & 2047;
    const int h  = (int)(ci >> 14) & 15;
    const int b  = (int)(ci >> 18);
    const size_t src = ((size_t)(b * Tn + t)) * C3n + h * HSn + d0;
    bf16x8 k8 = *(const bf16x8*)(qkv + src + Cn);
    bf16x8 v8 = *(const bf16x8*)(qkv + src + 2 * Cn);
    float kq[8], vq[8];
#pragma unroll
    for (int j = 0; j < 8; ++j) {
      kq[j] = fminf(fmaxf(rintf((float)k8[j] * kinv), -127.0f), 127.0f);
      vq[j] = fminf(fmaxf(rintf((float)v8[j] * vinv), -127.0f), 127.0f);
    }
    const size_t oi = ci * 8;
    f32x4 a0 = {kq[0], kq[1], kq[2], kq[3]};
    f32x4 a1 = {kq[4], kq[5], kq[6], kq[7]};
    *(f32x4*)(out + OUT_KQ + oi)     = a0;
    *(f32x4*)(out + OUT_KQ + oi + 4) = a1;
    float* vdst = out + OUT_VQ + oi;
#pragma unroll
    for (int j = 0; j < 8; ++j) vdst[j] = vq[j];
  }
}

// ============================================================
// Transposed-score MFMA flash attention, causal, double-buffered K/V pipeline.
// Block = (b,h,q-tile of 64), 4 waves x 16 q. S^T = K*Q^T (softmax state is a
// lane scalar). O^T = V^T*P^T. Ks/Vt double-buffered: global loads for tile
// kt+1 issued before compute of tile kt, waited after -> latency hidden.
// All LDS arrays XOR-swizzled on 16B chunks -> <=2-way (free). LDS = 40960 B
// -> exactly 4 blocks/CU.
__global__ __launch_bounds__(256, 4) void k_attn(const bf16* __restrict__ qkv,
                                                 bf16* __restrict__ y) {
  __shared__ bf16 Ks[2][64 * 64];
  __shared__ bf16 Vt[2][64 * 64];
  __shared__ bf16 Pt[4][16 * 64];

  const int tid = threadIdx.x;
  const int lane = tid & 63;
  const int w = tid >> 6;
  const int quad = lane >> 4;
  const int l15 = lane & 15;

  const int qt = 31 - (int)blockIdx.x;     // long blocks first
  const int bh = blockIdx.y;
  const int b = bh >> 4, h = bh & 15;
  const int q0 = qt * 64;

  const bf16* qkv_b = qkv + (size_t)b * Tn * C3n + h * HSn;
  const bf16* kbase = qkv_b + Cn;
  const bf16* vbase = qkv_b + 2 * Cn;
  bf16* Pw = Pt[w];

  // K staging: wave w covers row-groups g=w and g=w+4 (8 rows each).
  // lane -> row 8g+(lane>>3); source chunk (lane&7)^(row&7) lands at phys
  // chunk (lane&7) => logical chunk c of row r lives at phys c^(r&7).
  const int srow = lane >> 3;
  const int schunk = ((lane & 7) ^ (srow & 7)) * 8;

  // ---- prologue: K(0) -> Ks[0], V(0) -> Vt[0], Q frags from global ----
  g2l16(kbase + (size_t)(8 * w + srow) * C3n + schunk, (bf16*)Ks[0] + w * 512);
  g2l16(kbase + (size_t)(8 * (w + 4) + srow) * C3n + schunk, (bf16*)Ks[0] + (w + 4) * 512);
  bf16x8 v0 = *(const bf16x8*)(vbase + (size_t)lane * C3n + w * 8);
  bf16x8 v1 = *(const bf16x8*)(vbase + (size_t)lane * C3n + (w + 4) * 8);
  const bf16* qrow_p = qkv_b + (size_t)(q0 + 16 * w + l15) * C3n;
  bf16x8 qf[2];
  qf[0] = *(const bf16x8*)(qrow_p + quad * 8);
  qf[1] = *(const bf16x8*)(qrow_p + 32 + quad * 8);
  __builtin_amdgcn_s_waitcnt(0);
#pragma unroll
  for (int j = 0; j < 8; ++j) {   // Vt[d][kc] swizzled; d&7 == j
    Vt[0][(w * 8 + j) * 64 + (((lane >> 3) ^ j) << 3) + (lane & 7)] = v0[j];
    Vt[0][((w + 4) * 8 + j) * 64 + (((lane >> 3) ^ j) << 3) + (lane & 7)] = v1[j];
  }
  __syncthreads();

  f32x4 Od[4] = {};
  float m_i = -INFINITY, l_i = 0.0f;

  for (int kt = 0; kt <= qt; ++kt) {
    const int bsel = kt & 1;

    // ---- issue next tile's loads (consumed after compute) ----
    bf16x8 n0, n1;
    if (kt < qt) {
      const int kv1 = (kt + 1) * 64;
      g2l16(kbase + (size_t)(kv1 + 8 * w + srow) * C3n + schunk,
            (bf16*)Ks[bsel ^ 1] + w * 512);
      g2l16(kbase + (size_t)(kv1 + 8 * (w + 4) + srow) * C3n + schunk,
            (bf16*)Ks[bsel ^ 1] + (w + 4) * 512);
      n0 = *(const bf16x8*)(vbase + (size_t)(kv1 + lane) * C3n + w * 8);
      n1 = *(const bf16x8*)(vbase + (size_t)(kv1 + lane) * C3n + (w + 4) * 8);
    }

    // ---- S^T = K Q^T : D[m=kc][n=q] ----
    const bf16* KsB = Ks[bsel];
    f32x4 Sacc[4] = {};
#pragma unroll
    for (int ks = 0; ks < 2; ++ks)
#pragma unroll
      for (int nt = 0; nt < 4; ++nt) {
        const int rn = nt * 16 + l15;
        const int c = (ks * 4 + quad) ^ (rn & 7);
        bf16x8 kf = *(const bf16x8*)(KsB + rn * 64 + c * 8);
        Sacc[nt] = __builtin_amdgcn_mfma_f32_16x16x32_bf16(kf, qf[ks], Sacc[nt], 0, 0, 0);
      }

    // ---- online softmax: lane owns q = 16w+l15 ----
    const bool diag = (kt == qt);
    const int qrow = 16 * w + l15;
    float s[4][4];
    float mx = -INFINITY;
#pragma unroll
    for (int nt = 0; nt < 4; ++nt)
#pragma unroll
      for (int r = 0; r < 4; ++r) {
        float v = Sacc[nt][r] * 0.125f;
        if (diag && (nt * 16 + quad * 4 + r > qrow)) v = -INFINITY;
        s[nt][r] = v;
        mx = fmaxf(mx, v);
      }
    mx = fmaxf(mx, __shfl_xor(mx, 16));
    mx = fmaxf(mx, __shfl_xor(mx, 32));
    const float mn = fmaxf(m_i, mx);
    const float al = __expf(m_i - mn);
    m_i = mn;
    float rsum = 0.0f;
    bf16x4 pk[4];
#pragma unroll
    for (int nt = 0; nt < 4; ++nt)
#pragma unroll
      for (int r = 0; r < 4; ++r) {
        const float p = __expf(s[nt][r] - mn);
        rsum += p;
        pk[nt][r] = (bf16)p;
      }
    rsum += __shfl_xor(rsum, 16);
    rsum += __shfl_xor(rsum, 32);
    l_i = l_i * al + rsum;
#pragma unroll
    for (int dt = 0; dt < 4; ++dt) Od[dt] *= al;

    // P^T pack (wave-private, swizzled): row=l15(q), kc0=nt*16+quad*4
#pragma unroll
    for (int nt = 0; nt < 4; ++nt) {
      const int phys = (nt * 2 + (quad >> 1)) ^ (l15 & 7);
      *(bf16x4*)(Pw + l15 * 64 + phys * 8 + (quad & 1) * 4) = pk[nt];
    }

    // ---- O^T += V^T P^T ----
    const bf16* VtB = Vt[bsel];
#pragma unroll
    for (int ks2 = 0; ks2 < 2; ++ks2) {
      const int pc = (ks2 * 4 + quad) ^ (l15 & 7);
      bf16x8 pf = *(const bf16x8*)(Pw + l15 * 64 + pc * 8);
#pragma unroll
      for (int dt = 0; dt < 4; ++dt) {
        const int d = dt * 16 + l15;
        bf16x8 vf = *(const bf16x8*)(VtB + d * 64 + pc * 8);   // d&7 == l15&7
        Od[dt] = __builtin_amdgcn_mfma_f32_16x16x32_bf16(vf, pf, Od[dt], 0, 0, 0);
      }
    }

    // ---- drain next-tile loads, publish Vt[b^1], single barrier ----
    if (kt < qt) {
      __builtin_amdgcn_s_waitcnt(0);
#pragma unroll
      for (int j = 0; j < 8; ++j) {
        Vt[bsel ^ 1][(w * 8 + j) * 64 + (((lane >> 3) ^ j) << 3) + (lane & 7)] = n0[j];
        Vt[bsel ^ 1][((w + 4) * 8 + j) * 64 + (((lane >> 3) ^ j) << 3) + (lane & 7)] = n1[j];
      }
      __syncthreads();
    }
  }

  // ---- write y (B,T,C): lane owns q; d = dt*16 + quad*4 + r contiguous ----
  const float invl = 1.0f / l_i;
  const size_t yb = ((size_t)b * Tn + q0 + 16 * w + l15) * Cn + h * HSn;
#pragma unroll
  for (int dt = 0; dt < 4; ++dt) {
    bf16x4 o;
#pragma unroll
    for (int r = 0; r < 4; ++r) o[r] = (bf16)(Od[dt][r] * invl);
    *(bf16x4*)(y + yb + dt * 16 + quad * 4) = o;
  }
}

// ============================================================
extern "C" void kernel_launch(void* const* d_in, const int* in_sizes, int n_in,
                              void* d_out, int out_size, void* d_ws, size_t ws_size,
                              hipStream_t stream) {
  const float* x     = (const float*)d_in[0];
  const float* ln1w  = (const float*)d_in[1];
  const float* ln1b  = (const float*)d_in[2];
  const float* Wqkv  = (const float*)d_in[3];
  const float* bqkv  = (const float*)d_in[4];
  const float* Wo    = (const float*)d_in[5];
  const float* bo    = (const float*)d_in[6];
  const float* ln2w  = (const float*)d_in[7];
  const float* ln2b  = (const float*)d_in[8];
  const float* Wfc   = (const float*)d_in[9];
  const float* bfc   = (const float*)d_in[10];
  const float* Wpr   = (const float*)d_in[11];
  const float* bpr   = (const float*)d_in[12];

  char* ws = (char*)d_ws;
  bf16*  Wt_qkv = (bf16*)(ws + OFF_WT_QKV);
  bf16*  Wt_o   = (bf16*)(ws + OFF_WT_O);
  bf16*  Wt_fc  = (bf16*)(ws + OFF_WT_FC);
  bf16*  Wt_pr  = (bf16*)(ws + OFF_WT_PR);
  bf16*  h      = (bf16*)(ws + OFF_H);
  bf16*  ybf    = (bf16*)(ws + OFF_Y);
  float* x1     = (float*)(ws + OFF_X1);
  unsigned int* amax = (unsigned int*)(ws + OFF_AMAX);
  bf16*  qkvbf  = (bf16*)(ws + OFF_QKV);
  bf16*  g      = (bf16*)(ws + OFF_G);
  float* out    = (float*)d_out;

  const dim3 tb(32, 8);
  k_transpose<<<dim3(96, 32),  tb, 0, stream>>>(Wqkv, Wt_qkv, 1024, 3072);
  k_transpose<<<dim3(32, 32),  tb, 0, stream>>>(Wo,   Wt_o,   1024, 1024);
  k_transpose<<<dim3(128, 32), tb, 0, stream>>>(Wfc,  Wt_fc,  1024, 4096);
  k_transpose<<<dim3(32, 128), tb, 0, stream>>>(Wpr,  Wt_pr,  4096, 1024);
  k_init<<<1, 64, 0, stream>>>(amax);

  k_ln<<<BTn, 256, 0, stream>>>(x, ln1w, ln1b, h);
  // qkv = h @ Wqkv + b, with fused per-tensor absmax of K and V slices
  k_gemm<true, false, false, true><<<dim3(64, 24), 256, 0, stream>>>(h, Wt_qkv, bqkv, nullptr, qkvbf, amax, 8192, 3072, 1024);
  k_quant<<<2048, 256, 0, stream>>>(qkvbf, amax, out);
  k_attn<<<dim3(32, 64), 256, 0, stream>>>(qkvbf, ybf);
  k_gemm<false, true, false, false><<<dim3(64, 8), 256, 0, stream>>>(ybf, Wt_o, bo, x, x1, nullptr, 8192, 1024, 1024);
  k_ln<<<BTn, 256, 0, stream>>>(x1, ln2w, ln2b, h);
  k_gemm<true, false, true, false><<<dim3(64, 32), 256, 0, stream>>>(h, Wt_fc, bfc, nullptr, g, nullptr, 8192, 4096, 1024);
  k_gemm<false, true, false, false><<<dim3(64, 8), 256, 0, stream>>>(g, Wt_pr, bpr, x1, out, nullptr, 8192, 1024, 4096);
}

// Round 5
// 573.939 us; speedup vs baseline: 4.6434x; 1.1888x over previous
//
#include <hip/hip_runtime.h>
#include <cmath>

typedef __bf16 bf16;
typedef float f32x4 __attribute__((ext_vector_type(4)));
typedef __bf16 bf16x4 __attribute__((ext_vector_type(4)));
typedef __bf16 bf16x8 __attribute__((ext_vector_type(8)));

#define DEVI __device__ __forceinline__

// ---- problem dims ----
constexpr int Bn = 4, Tn = 2048, Cn = 1024, Hn = 16, HSn = 64;
constexpr int C3n = 3 * Cn;      // 3072
constexpr int BTn = Bn * Tn;     // 8192

// ---- workspace layout (bytes) ----
constexpr size_t OFF_WT_QKV = 0;           // 3072x1024 bf16
constexpr size_t OFF_WT_O   = 6291456;     // 1024x1024 bf16
constexpr size_t OFF_WT_FC  = 8388608;     // 4096x1024 bf16
constexpr size_t OFF_WT_PR  = 16777216;    // 1024x4096 bf16
constexpr size_t OFF_H      = 25165824;    // 8192x1024 bf16 (h / h2)
constexpr size_t OFF_Y      = 41943040;    // 8192x1024 bf16 (attn out)
constexpr size_t OFF_X1     = 58720256;    // 8192x1024 f32  (resid1)
constexpr size_t OFF_AMAX   = 92274688;    // 2 x u32
constexpr size_t OFF_QKV    = 92274944;    // 8192x3072 bf16
constexpr size_t OFF_G      = OFF_QKV;     // 8192x4096 bf16 (aliases qkv, dead by then)

// ---- d_out layout (float elements) ----
constexpr size_t OUT_X  = 0;          // (B,T,C)
constexpr size_t OUT_KQ = 8388608;    // (B,H,T,HS)
constexpr size_t OUT_KS = 16777216;   // scalar
constexpr size_t OUT_VQ = 16777217;   // (B,H,T,HS)
constexpr size_t OUT_VS = 25165825;   // scalar

// ============================================================
DEVI void g2l16(const void* g, void* l) {
  __builtin_amdgcn_global_load_lds(
      (__attribute__((address_space(1))) void*)g,
      (__attribute__((address_space(3))) void*)l, 16, 0, 0);
}

// exact-grade GELU: Abramowitz-Stegun 7.1.26 erf (|eps|<=1.5e-7), ~15 VALU + 1 exp
DEVI float gelu_f(float x) {
  const float ax = fabsf(x) * 0.7071067811865476f;
  const float t = 1.0f / (1.0f + 0.3275911f * ax);
  const float p = t * (0.254829592f + t * (-0.284496736f +
                  t * (1.421413741f + t * (-1.453152027f + t * 1.061405429f))));
  float er = 1.0f - p * __expf(-ax * ax);
  er = (x < 0.0f) ? -er : er;
  return 0.5f * x * (1.0f + er);
}

// ============================================================
// transpose + cast: W (K x N) f32 -> Wt (N x K) bf16
__global__ __launch_bounds__(256) void k_transpose(const float* __restrict__ W,
                                                   bf16* __restrict__ Wt,
                                                   int K, int N) {
  __shared__ float tile[32][33];
  const int n0 = blockIdx.x * 32, k0 = blockIdx.y * 32;
  const int tx = threadIdx.x, ty = threadIdx.y;   // block (32,8)
#pragma unroll
  for (int i = 0; i < 4; ++i) {
    int k = k0 + ty + i * 8;
    tile[ty + i * 8][tx] = W[(size_t)k * N + (n0 + tx)];
  }
  __syncthreads();
#pragma unroll
  for (int i = 0; i < 4; ++i) {
    int n = n0 + ty + i * 8;
    Wt[(size_t)n * K + (k0 + tx)] = (bf16)tile[tx][ty + i * 8];
  }
}

// ============================================================
// LayerNorm row of 1024, f32 in -> bf16 out.
__global__ __launch_bounds__(256) void k_ln(const float* __restrict__ x,
                                            const float* __restrict__ g,
                                            const float* __restrict__ b,
                                            bf16* __restrict__ out) {
  __shared__ float red[8];
  const int row = blockIdx.x, tid = threadIdx.x;
  const int lane = tid & 63, wv = tid >> 6;
  f32x4 v = ((const f32x4*)(x + (size_t)row * Cn))[tid];

  float s = v[0] + v[1] + v[2] + v[3];
  s += __shfl_down(s, 32); s += __shfl_down(s, 16); s += __shfl_down(s, 8);
  s += __shfl_down(s, 4);  s += __shfl_down(s, 2);  s += __shfl_down(s, 1);
  if (!lane) red[wv] = s;
  __syncthreads();
  const float mean = (red[0] + red[1] + red[2] + red[3]) * (1.0f / 1024.0f);
  __syncthreads();

  f32x4 d = v - mean;
  float s2 = d[0]*d[0] + d[1]*d[1] + d[2]*d[2] + d[3]*d[3];
  s2 += __shfl_down(s2, 32); s2 += __shfl_down(s2, 16); s2 += __shfl_down(s2, 8);
  s2 += __shfl_down(s2, 4);  s2 += __shfl_down(s2, 2);  s2 += __shfl_down(s2, 1);
  if (!lane) red[wv] = s2;
  __syncthreads();
  const float var = (red[0] + red[1] + red[2] + red[3]) * (1.0f / 1024.0f);
  const float inv = rsqrtf(var + 1e-5f);

  f32x4 gw = ((const f32x4*)g)[tid];
  f32x4 bb = ((const f32x4*)b)[tid];
  bf16x4 o;
#pragma unroll
  for (int j = 0; j < 4; ++j) o[j] = (bf16)(d[j] * inv * gw[j] + bb[j]);
  *(bf16x4*)(out + (size_t)row * Cn + tid * 4) = o;
}

// ============================================================
// MFMA GEMM, BK=64, XOR-swizzled LDS (logical chunk c of row r at phys c^(r&7)).
// C(MxN) = A(MxK,bf16)*Bt(NxK,bf16)^T + bias [+GELU] [+res] [+absmax]
template <bool BF16OUT, bool RES, bool GELU, bool AMAX>
__global__ __launch_bounds__(256) void k_gemm(const bf16* __restrict__ A,
                                              const bf16* __restrict__ Bt,
                                              const float* __restrict__ bias,
                                              const float* __restrict__ res,
                                              void* __restrict__ Cout,
                                              unsigned int* __restrict__ amax,
                                              int M, int N, int K) {
  __shared__ bf16 As[128 * 64];
  __shared__ bf16 Bs[128 * 64];
  __shared__ float redA[4];
  const int tid = threadIdx.x;
  const int lane = tid & 63;
  const int w = tid >> 6;
  const int wm = w & 1, wn = w >> 1;
  const int l15 = lane & 15, quad = lane >> 4;
  const int m0 = blockIdx.x * 128, n0 = blockIdx.y * 128;

  // staging: lane -> row 8g+(lane>>3), phys chunk lane&7; source logical
  // chunk (lane&7)^(lane>>3) so logical c lands at phys c^(row&7).
  const int srow = lane >> 3;
  const int sch = ((lane & 7) ^ srow) * 8;
  const bf16* aBase = A  + (size_t)(m0 + srow) * K + sch;
  const bf16* bBase = Bt + (size_t)(n0 + srow) * K + sch;

  f32x4 acc[4][4] = {};
  const int kIters = K >> 6;
  for (int kt = 0; kt < kIters; ++kt) {
    const size_t kOff = (size_t)kt * 64;
#pragma unroll
    for (int j = 0; j < 4; ++j) {
      const int g = w + 4 * j;
      g2l16(aBase + (size_t)(8 * g) * K + kOff, As + g * 512);
      g2l16(bBase + (size_t)(8 * g) * K + kOff, Bs + g * 512);
    }
    __builtin_amdgcn_s_waitcnt(0);
    __syncthreads();

#pragma unroll
    for (int kk = 0; kk < 2; ++kk) {
      bf16x8 af[4], bv[4];
#pragma unroll
      for (int mt = 0; mt < 4; ++mt) {
        const int m = wm * 64 + mt * 16 + l15;
        const int c = ((kk * 4 + quad) ^ (l15 & 7)) * 8;
        af[mt] = *(const bf16x8*)(As + m * 64 + c);
      }
#pragma unroll
      for (int nt = 0; nt < 4; ++nt) {
        const int n = wn * 64 + nt * 16 + l15;
        const int c = ((kk * 4 + quad) ^ (l15 & 7)) * 8;
        bv[nt] = *(const bf16x8*)(Bs + n * 64 + c);
      }
#pragma unroll
      for (int mt = 0; mt < 4; ++mt)
#pragma unroll
        for (int nt = 0; nt < 4; ++nt)
          acc[mt][nt] = __builtin_amdgcn_mfma_f32_16x16x32_bf16(af[mt], bv[nt], acc[mt][nt], 0, 0, 0);
    }
    __syncthreads();
  }

  const int colB = n0 + wn * 64 + l15;
  const int rowB = m0 + wm * 64 + (quad << 2);
  float lm = 0.0f;
#pragma unroll
  for (int mt = 0; mt < 4; ++mt) {
#pragma unroll
    for (int nt = 0; nt < 4; ++nt) {
      const int col = colB + nt * 16;
      const float bval = bias[col];
#pragma unroll
      for (int r = 0; r < 4; ++r) {
        const int row = rowB + mt * 16 + r;
        float val = acc[mt][nt][r] + bval;
        if (GELU) val = gelu_f(val);
        if (RES)  val += res[(size_t)row * N + col];
        if (AMAX) lm = fmaxf(lm, fabsf(val));
        if (BF16OUT) ((bf16*)Cout)[(size_t)row * N + col] = (bf16)val;
        else         ((float*)Cout)[(size_t)row * N + col] = val;
      }
    }
  }

  if (AMAX) {
    const int cls = n0 >> 10;   // 0=Q, 1=K, 2=V
    if (cls > 0) {
      lm = fmaxf(lm, __shfl_xor(lm, 1));
      lm = fmaxf(lm, __shfl_xor(lm, 2));
      lm = fmaxf(lm, __shfl_xor(lm, 4));
      lm = fmaxf(lm, __shfl_xor(lm, 8));
      lm = fmaxf(lm, __shfl_xor(lm, 16));
      lm = fmaxf(lm, __shfl_xor(lm, 32));
      if (!lane) redA[w] = lm;
      __syncthreads();
      if (tid == 0) {
        const float m4 = fmaxf(fmaxf(redA[0], redA[1]), fmaxf(redA[2], redA[3]));
        atomicMax(amax + (cls - 1), __float_as_uint(m4));
      }
    }
  }
}

// ============================================================
__global__ __launch_bounds__(256) void k_init(unsigned int* amax) {
  if (threadIdx.x < 2) amax[threadIdx.x] = 0u;
}

__global__ __launch_bounds__(256) void k_quant(const bf16* __restrict__ qkv,
                                               const unsigned int* __restrict__ amax,
                                               float* __restrict__ out) {
  const float ka = __uint_as_float(amax[0]);
  const float va = __uint_as_float(amax[1]);
  const float ks = ka > 0.0f ? ka / 127.0f : 1.0f;
  const float vs = va > 0.0f ? va / 127.0f : 1.0f;
  if (blockIdx.x == 0 && threadIdx.x == 0) { out[OUT_KS] = ks; out[OUT_VS] = vs; }
  const float kinv = 1.0f / ks, vinv = 1.0f / vs;
  const size_t nchunks = 1048576;
  const size_t stride = (size_t)gridDim.x * blockDim.x;
  for (size_t ci = (size_t)blockIdx.x * blockDim.x + threadIdx.x; ci < nchunks; ci += stride) {
    const int d0 = (int)(ci & 7) * 8;
    const int t  = (int)(ci >> 3) & 2047;
    const int h  = (int)(ci >> 14) & 15;
    const int b  = (int)(ci >> 18);
    const size_t src = ((size_t)(b * Tn + t)) * C3n + h * HSn + d0;
    bf16x8 k8 = *(const bf16x8*)(qkv + src + Cn);
    bf16x8 v8 = *(const bf16x8*)(qkv + src + 2 * Cn);
    float kq[8], vq[8];
#pragma unroll
    for (int j = 0; j < 8; ++j) {
      kq[j] = fminf(fmaxf(rintf((float)k8[j] * kinv), -127.0f), 127.0f);
      vq[j] = fminf(fmaxf(rintf((float)v8[j] * vinv), -127.0f), 127.0f);
    }
    const size_t oi = ci * 8;
    f32x4 a0 = {kq[0], kq[1], kq[2], kq[3]};
    f32x4 a1 = {kq[4], kq[5], kq[6], kq[7]};
    *(f32x4*)(out + OUT_KQ + oi)     = a0;
    *(f32x4*)(out + OUT_KQ + oi + 4) = a1;
    float* vdst = out + OUT_VQ + oi;
#pragma unroll
    for (int j = 0; j < 8; ++j) vdst[j] = vq[j];
  }
}

// ============================================================
// Transposed-score MFMA flash attention, causal, q-tile=128 (2 q-groups/wave),
// double-buffered K/V. K/V fragments are wave-invariant -> amortized over 2
// q-groups. Block = (b,h,128 q rows), 4 waves. LDS 48 KB -> 3 blocks/CU.
__global__ __launch_bounds__(256, 3) void k_attn(const bf16* __restrict__ qkv,
                                                 bf16* __restrict__ y) {
  __shared__ bf16 Ks[2][64 * 64];
  __shared__ bf16 Vt[2][64 * 64];
  __shared__ bf16 Pt[4][2][16 * 64];   // per wave, per q-group

  const int tid = threadIdx.x;
  const int lane = tid & 63;
  const int w = tid >> 6;
  const int quad = lane >> 4;
  const int l15 = lane & 15;

  const int bh = blockIdx.x;               // fastest dim: big tiles dispatch first
  const int qt = 15 - (int)blockIdx.y;
  const int b = bh >> 4, h = bh & 15;
  const int q0 = qt * 128;
  const int ktMax = 2 * qt + 1;

  const bf16* qkv_b = qkv + (size_t)b * Tn * C3n + h * HSn;
  const bf16* kbase = qkv_b + Cn;
  const bf16* vbase = qkv_b + 2 * Cn;

  const int srow = lane >> 3;
  const int schunk = ((lane & 7) ^ srow) * 8;

  // ---- Q fragments for both groups (from global, once) ----
  const bf16* q0p = qkv_b + (size_t)(q0 + 16 * w + l15) * C3n;
  const bf16* q1p = q0p + (size_t)64 * C3n;
  bf16x8 qf[2][2];
  qf[0][0] = *(const bf16x8*)(q0p + quad * 8);
  qf[0][1] = *(const bf16x8*)(q0p + 32 + quad * 8);
  qf[1][0] = *(const bf16x8*)(q1p + quad * 8);
  qf[1][1] = *(const bf16x8*)(q1p + 32 + quad * 8);

  // ---- prologue: K(0), V(0) ----
  g2l16(kbase + (size_t)(8 * w + srow) * C3n + schunk, (bf16*)Ks[0] + w * 512);
  g2l16(kbase + (size_t)(8 * (w + 4) + srow) * C3n + schunk, (bf16*)Ks[0] + (w + 4) * 512);
  bf16x8 v0 = *(const bf16x8*)(vbase + (size_t)lane * C3n + w * 8);
  bf16x8 v1 = *(const bf16x8*)(vbase + (size_t)lane * C3n + (w + 4) * 8);
  __builtin_amdgcn_s_waitcnt(0);
#pragma unroll
  for (int j = 0; j < 8; ++j) {   // Vt[d][kc] swizzled; d&7 == j
    Vt[0][(w * 8 + j) * 64 + ((srow ^ j) << 3) + (lane & 7)] = v0[j];
    Vt[0][((w + 4) * 8 + j) * 64 + ((srow ^ j) << 3) + (lane & 7)] = v1[j];
  }
  __syncthreads();

  f32x4 Od[2][4] = {};
  float m_i[2] = {-INFINITY, -INFINITY};
  float l_i[2] = {0.0f, 0.0f};

  for (int kt = 0; kt <= ktMax; ++kt) {
    const int bsel = kt & 1;

    // ---- issue next tile's loads ----
    bf16x8 nv0, nv1;
    if (kt < ktMax) {
      const int kv1 = (kt + 1) * 64;
      g2l16(kbase + (size_t)(kv1 + 8 * w + srow) * C3n + schunk,
            (bf16*)Ks[bsel ^ 1] + w * 512);
      g2l16(kbase + (size_t)(kv1 + 8 * (w + 4) + srow) * C3n + schunk,
            (bf16*)Ks[bsel ^ 1] + (w + 4) * 512);
      nv0 = *(const bf16x8*)(vbase + (size_t)(kv1 + lane) * C3n + w * 8);
      nv1 = *(const bf16x8*)(vbase + (size_t)(kv1 + lane) * C3n + (w + 4) * 8);
    }

    // ---- S^T = K Q^T for both q-groups (K frags shared) ----
    const bf16* KsB = Ks[bsel];
    f32x4 S0[4] = {}, S1[4] = {};
#pragma unroll
    for (int ks = 0; ks < 2; ++ks)
#pragma unroll
      for (int nt = 0; nt < 4; ++nt) {
        const int rn = nt * 16 + l15;
        const int c = ((ks * 4 + quad) ^ (l15 & 7)) * 8;
        bf16x8 kf = *(const bf16x8*)(KsB + rn * 64 + c);
        S0[nt] = __builtin_amdgcn_mfma_f32_16x16x32_bf16(kf, qf[0][ks], S0[nt], 0, 0, 0);
        S1[nt] = __builtin_amdgcn_mfma_f32_16x16x32_bf16(kf, qf[1][ks], S1[nt], 0, 0, 0);
      }

    // ---- online softmax per group (lane owns q = g*64 + 16w + l15) ----
    // mask threshold on local kv index nt*16+quad*4+r:
    //   g0: kt<2qt -> none(64); kt==2qt -> diag; kt==2qt+1 -> all(-1)
    //   g1: kt<ktMax -> none;  kt==ktMax -> diag
    const int qloc = 16 * w + l15;
    const int th[2] = { kt < 2 * qt ? 64 : (kt == 2 * qt ? qloc : -1),
                        kt < ktMax ? 64 : qloc };
    f32x4* Sg[2] = {S0, S1};
#pragma unroll
    for (int g = 0; g < 2; ++g) {
      float s[4][4];
      float mx = -INFINITY;
#pragma unroll
      for (int nt = 0; nt < 4; ++nt)
#pragma unroll
        for (int r = 0; r < 4; ++r) {
          float v = Sg[g][nt][r] * 0.125f;
          if (nt * 16 + quad * 4 + r > th[g]) v = -INFINITY;
          s[nt][r] = v;
          mx = fmaxf(mx, v);
        }
      mx = fmaxf(mx, __shfl_xor(mx, 16));
      mx = fmaxf(mx, __shfl_xor(mx, 32));
      const float mn = fmaxf(m_i[g], mx);
      const float al = __expf(m_i[g] - mn);
      m_i[g] = mn;
      float rsum = 0.0f;
      bf16x4 pk[4];
#pragma unroll
      for (int nt = 0; nt < 4; ++nt)
#pragma unroll
        for (int r = 0; r < 4; ++r) {
          const float p = __expf(s[nt][r] - mn);
          rsum += p;
          pk[nt][r] = (bf16)p;
        }
      rsum += __shfl_xor(rsum, 16);
      rsum += __shfl_xor(rsum, 32);
      l_i[g] = l_i[g] * al + rsum;
#pragma unroll
      for (int dt = 0; dt < 4; ++dt) Od[g][dt] *= al;
      // P^T pack (wave+group private, swizzled)
#pragma unroll
      for (int nt = 0; nt < 4; ++nt) {
        const int phys = (nt * 2 + (quad >> 1)) ^ (l15 & 7);
        *(bf16x4*)(&Pt[w][g][0] + l15 * 64 + phys * 8 + (quad & 1) * 4) = pk[nt];
      }
    }

    // ---- O^T += V^T P^T (V frags shared across groups) ----
    const bf16* VtB = Vt[bsel];
#pragma unroll
    for (int ks2 = 0; ks2 < 2; ++ks2) {
      const int pc = ((ks2 * 4 + quad) ^ (l15 & 7)) * 8;
      bf16x8 pf0 = *(const bf16x8*)(&Pt[w][0][0] + l15 * 64 + pc);
      bf16x8 pf1 = *(const bf16x8*)(&Pt[w][1][0] + l15 * 64 + pc);
#pragma unroll
      for (int dt = 0; dt < 4; ++dt) {
        const int d = dt * 16 + l15;
        bf16x8 vf = *(const bf16x8*)(VtB + d * 64 + pc);   // d&7 == l15&7
        Od[0][dt] = __builtin_amdgcn_mfma_f32_16x16x32_bf16(vf, pf0, Od[0][dt], 0, 0, 0);
        Od[1][dt] = __builtin_amdgcn_mfma_f32_16x16x32_bf16(vf, pf1, Od[1][dt], 0, 0, 0);
      }
    }

    // ---- drain next-tile loads, publish Vt[b^1], one barrier ----
    if (kt < ktMax) {
      __builtin_amdgcn_s_waitcnt(0);
#pragma unroll
      for (int j = 0; j < 8; ++j) {
        Vt[bsel ^ 1][(w * 8 + j) * 64 + ((srow ^ j) << 3) + (lane & 7)] = nv0[j];
        Vt[bsel ^ 1][((w + 4) * 8 + j) * 64 + ((srow ^ j) << 3) + (lane & 7)] = nv1[j];
      }
      __syncthreads();
    }
  }

  // ---- write y (B,T,C) ----
#pragma unroll
  for (int g = 0; g < 2; ++g) {
    const float invl = 1.0f / l_i[g];
    const size_t yb = ((size_t)b * Tn + q0 + g * 64 + 16 * w + l15) * Cn + h * HSn;
#pragma unroll
    for (int dt = 0; dt < 4; ++dt) {
      bf16x4 o;
#pragma unroll
      for (int r = 0; r < 4; ++r) o[r] = (bf16)(Od[g][dt][r] * invl);
      *(bf16x4*)(y + yb + dt * 16 + quad * 4) = o;
    }
  }
}

// ============================================================
extern "C" void kernel_launch(void* const* d_in, const int* in_sizes, int n_in,
                              void* d_out, int out_size, void* d_ws, size_t ws_size,
                              hipStream_t stream) {
  const float* x     = (const float*)d_in[0];
  const float* ln1w  = (const float*)d_in[1];
  const float* ln1b  = (const float*)d_in[2];
  const float* Wqkv  = (const float*)d_in[3];
  const float* bqkv  = (const float*)d_in[4];
  const float* Wo    = (const float*)d_in[5];
  const float* bo    = (const float*)d_in[6];
  const float* ln2w  = (const float*)d_in[7];
  const float* ln2b  = (const float*)d_in[8];
  const float* Wfc   = (const float*)d_in[9];
  const float* bfc   = (const float*)d_in[10];
  const float* Wpr   = (const float*)d_in[11];
  const float* bpr   = (const float*)d_in[12];

  char* ws = (char*)d_ws;
  bf16*  Wt_qkv = (bf16*)(ws + OFF_WT_QKV);
  bf16*  Wt_o   = (bf16*)(ws + OFF_WT_O);
  bf16*  Wt_fc  = (bf16*)(ws + OFF_WT_FC);
  bf16*  Wt_pr  = (bf16*)(ws + OFF_WT_PR);
  bf16*  h      = (bf16*)(ws + OFF_H);
  bf16*  ybf    = (bf16*)(ws + OFF_Y);
  float* x1     = (float*)(ws + OFF_X1);
  unsigned int* amax = (unsigned int*)(ws + OFF_AMAX);
  bf16*  qkvbf  = (bf16*)(ws + OFF_QKV);
  bf16*  g      = (bf16*)(ws + OFF_G);
  float* out    = (float*)d_out;

  const dim3 tb(32, 8);
  k_transpose<<<dim3(96, 32),  tb, 0, stream>>>(Wqkv, Wt_qkv, 1024, 3072);
  k_transpose<<<dim3(32, 32),  tb, 0, stream>>>(Wo,   Wt_o,   1024, 1024);
  k_transpose<<<dim3(128, 32), tb, 0, stream>>>(Wfc,  Wt_fc,  1024, 4096);
  k_transpose<<<dim3(32, 128), tb, 0, stream>>>(Wpr,  Wt_pr,  4096, 1024);
  k_init<<<1, 64, 0, stream>>>(amax);

  k_ln<<<BTn, 256, 0, stream>>>(x, ln1w, ln1b, h);
  // qkv = h @ Wqkv + b, fused per-tensor absmax of K,V
  k_gemm<true, false, false, true><<<dim3(64, 24), 256, 0, stream>>>(h, Wt_qkv, bqkv, nullptr, qkvbf, amax, 8192, 3072, 1024);
  k_quant<<<2048, 256, 0, stream>>>(qkvbf, amax, out);
  k_attn<<<dim3(64, 16), 256, 0, stream>>>(qkvbf, ybf);
  k_gemm<false, true, false, false><<<dim3(64, 8), 256, 0, stream>>>(ybf, Wt_o, bo, x, x1, nullptr, 8192, 1024, 1024);
  k_ln<<<BTn, 256, 0, stream>>>(x1, ln2w, ln2b, h);
  k_gemm<true, false, true, false><<<dim3(64, 32), 256, 0, stream>>>(h, Wt_fc, bfc, nullptr, g, nullptr, 8192, 4096, 1024);
  k_gemm<false, true, false, false><<<dim3(64, 8), 256, 0, stream>>>(g, Wt_pr, bpr, x1, out, nullptr, 8192, 1024, 4096);
}